// Round 5
// baseline (2904.725 us; speedup 1.0000x reference)
//
#include <hip/hip_runtime.h>
#include <math.h>

#define NH    12
#define SEQ   1024
#define DH    64
#define HID   768
#define BATCH 16
#define MTOT  (BATCH*SEQ)   // 16384
#define KDIM  HID           // 768

typedef __attribute__((ext_vector_type(8))) short short8;
typedef __attribute__((ext_vector_type(8))) unsigned short ushort8;
typedef __attribute__((ext_vector_type(4))) float float4v;

__device__ __forceinline__ float bf2f(unsigned short u) {
    union { unsigned int i; float f; } v; v.i = ((unsigned int)u) << 16; return v.f;
}
__device__ __forceinline__ unsigned short f2bf(float f) {
    union { float f; unsigned int i; } v; v.f = f;
    unsigned int x = v.i;
    return (unsigned short)((x + 0x7FFFu + ((x >> 16) & 1u)) >> 16);  // RNE
}
__device__ __forceinline__ float loadf(const void* p, size_t i, bool f32) {
    return f32 ? ((const float*)p)[i] : bf2f(((const unsigned short*)p)[i]);
}
template<bool F32>
__device__ __forceinline__ short8 load8(const void* p, size_t i) {
    if constexpr (F32) {
        const float* fp = (const float*)p + i;
        short8 r;
#pragma unroll
        for (int e = 0; e < 8; e++) r[e] = (short)f2bf(fp[e]);
        return r;
    } else {
        return *(const short8*)((const unsigned short*)p + i);
    }
}
// Ootomo split: f = hi + lo with hi = bf16(f), lo = bf16(f - hi).
template<bool F32>
__device__ __forceinline__ void load8_split(const void* p, size_t i,
                                            short8& hi, short8& lo) {
#pragma unroll
    for (int e = 0; e < 8; e++) {
        const float f = F32 ? ((const float*)p)[i + e]
                            : bf2f(((const unsigned short*)p)[i + e]);
        const unsigned short h = f2bf(f);
        hi[e] = (short)h;
        lo[e] = (short)f2bf(f - bf2f(h));
    }
}

// Runtime dtype classifier for x (flag=1 => fp32 inputs).
__global__ __launch_bounds__(256) void detect_kernel(
    const unsigned short* __restrict__ x, unsigned int* __restrict__ flag)
{
    __shared__ int cnt[256];
    const int tid = threadIdx.x;
    int local = 0;
    for (int i = tid; i < 1024; i += 256) {
        const unsigned short u = x[i];
        const int e = (u >> 7) & 0xFF;
        if ((e >= 96 && e <= 134) || ((u & 0x7FFF) == 0)) local++;
    }
    cnt[tid] = local;
    __syncthreads();
    for (int s = 128; s > 0; s >>= 1) {
        if (tid < s) cnt[tid] += cnt[tid + s];
        __syncthreads();
    }
    if (tid == 0) flag[0] = (cnt[0] < 900) ? 1u : 0u;
}

// Fast single-bf16 core. MODE 2: A = x (M,K). MODE 3: A = O bf16 packed at the
// head of each 128-ushort row slot of the (B,H,S,D) fp32 Q buffer.
template<int MODE, bool AF32, bool BF32>
__device__ __forceinline__ void gemm_core(
    const void* __restrict__ A, const void* __restrict__ W,
    int m_blk, int n_blk, int l16, int quad, float4v acc[4][4])
{
    int mrow[4], nrow[4];
#pragma unroll
    for (int i = 0; i < 4; i++) { mrow[i] = m_blk + i * 16 + l16; nrow[i] = n_blk + i * 16 + l16; }

    for (int k0 = 0; k0 < KDIM; k0 += 32) {
        const int kk = quad * 8 + k0;
        short8 a[4], b[4];
#pragma unroll
        for (int im = 0; im < 4; im++) {
            size_t idx;
            if constexpr (MODE == 3) {
                idx = ((size_t)((mrow[im] >> 10) * NH + (kk >> 6)) * SEQ + (mrow[im] & (SEQ - 1)))
                      * (DH * 2) + (kk & (DH - 1));
            } else {
                idx = (size_t)mrow[im] * KDIM + kk;
            }
            a[im] = load8<AF32>(A, idx);
        }
#pragma unroll
        for (int in = 0; in < 4; in++)
            b[in] = load8<BF32>(W, (size_t)nrow[in] * KDIM + kk);
#pragma unroll
        for (int im = 0; im < 4; im++)
#pragma unroll
            for (int in = 0; in < 4; in++)
                acc[im][in] = __builtin_amdgcn_mfma_f32_16x16x32_bf16(
                    a[im], b[in], acc[im][in], 0, 0, 0);
    }
}

// Precise bf16x3 core (Q/K projections): A@W^T with Ootomo split;
// error ~2^-17 rel instead of 2^-9 — the RSE rem-cascade amplifies logit
// noise ~100x at the tail, so single-bf16 here fails the 2% bound.
template<bool F32>
__device__ __forceinline__ void gemm_core_precise(
    const void* __restrict__ A, const void* __restrict__ W,
    int m_blk, int n_blk, int l16, int quad, float4v acc[4][4])
{
    int mrow[4], nrow[4];
#pragma unroll
    for (int i = 0; i < 4; i++) { mrow[i] = m_blk + i * 16 + l16; nrow[i] = n_blk + i * 16 + l16; }

    for (int k0 = 0; k0 < KDIM; k0 += 32) {
        const int kk = quad * 8 + k0;
        short8 ah[4], al[4], bh[4], bl[4];
#pragma unroll
        for (int im = 0; im < 4; im++)
            load8_split<F32>(A, (size_t)mrow[im] * KDIM + kk, ah[im], al[im]);
#pragma unroll
        for (int in = 0; in < 4; in++)
            load8_split<F32>(W, (size_t)nrow[in] * KDIM + kk, bh[in], bl[in]);
#pragma unroll
        for (int im = 0; im < 4; im++)
#pragma unroll
            for (int in = 0; in < 4; in++) {
                acc[im][in] = __builtin_amdgcn_mfma_f32_16x16x32_bf16(
                    ah[im], bh[in], acc[im][in], 0, 0, 0);
                acc[im][in] = __builtin_amdgcn_mfma_f32_16x16x32_bf16(
                    al[im], bh[in], acc[im][in], 0, 0, 0);
                acc[im][in] = __builtin_amdgcn_mfma_f32_16x16x32_bf16(
                    ah[im], bl[in], acc[im][in], 0, 0, 0);
            }
    }
}

// MODE 0: +bias +rope *0.125 -> FP32 (B,H,S,D)   (Q, precise)
// MODE 1: +bias +rope        -> FP32 (B,H,S,D)   (K, precise)
// MODE 2: +bias              -> BF16 (B,H,S,D)   (V)
// MODE 3: +bias              -> d_out row-major (M,N), dtype per flag
template<int MODE>
__global__ __launch_bounds__(256) void gemm_nt(
    const void* __restrict__ A, const void* __restrict__ W,
    const void* __restrict__ bias, const void* __restrict__ cosc,
    const void* __restrict__ sinc, const unsigned int* __restrict__ flag,
    void* __restrict__ Out)
{
    const int tid  = threadIdx.x;
    const int wid  = tid >> 6;
    const int lane = tid & 63;
    const int quad = lane >> 4;
    const int l16  = lane & 15;
    const int m_blk = blockIdx.x * 128 + (wid >> 1) * 64;
    const int n_blk = blockIdx.y * 128 + (wid & 1) * 64;
    const bool f32 = (flag[0] != 0u);

    float4v acc[4][4];
#pragma unroll
    for (int i = 0; i < 4; i++)
#pragma unroll
        for (int j = 0; j < 4; j++) acc[i][j] = (float4v)(0.f);

    if constexpr (MODE <= 1) {
        if (f32) gemm_core_precise<true >(A, W, m_blk, n_blk, l16, quad, acc);
        else     gemm_core_precise<false>(A, W, m_blk, n_blk, l16, quad, acc);
    } else {
        if (f32) gemm_core<MODE, (MODE != 3), true >(A, W, m_blk, n_blk, l16, quad, acc);
        else     gemm_core<MODE, false,       false>(A, W, m_blk, n_blk, l16, quad, acc);
    }

#pragma unroll
    for (int im = 0; im < 4; im++) {
#pragma unroll
        for (int in = 0; in < 4; in++) {
            const int col = n_blk + in * 16 + l16;
            const float bval = loadf(bias, col, f32);
#pragma unroll
            for (int r = 0; r < 4; r++) {
                const int row = m_blk + im * 16 + quad * 4 + r;
                float v = acc[im][in][r] + bval;
                if (MODE <= 1) {
                    const int s  = row & (SEQ - 1);
                    const int d  = col & (DH - 1);
                    const int d2 = d >> 1;
                    const float c  = loadf(cosc, s * (DH / 2) + d2, f32);
                    const float sn = loadf(sinc, s * (DH / 2) + d2, f32);
                    const float p = __shfl_xor(v, 1);  // lane^1 <-> d^1, same row
                    float o = (d & 1) ? (v * c + p * sn) : (v * c - p * sn);
                    if (MODE == 0) o *= 0.125f;
                    const int b = row >> 10, h = col >> 6;
                    ((float*)Out)[((size_t)(b * NH + h) * SEQ + s) * DH + d] = o;
                } else if (MODE == 2) {
                    const int s = row & (SEQ - 1);
                    const int b = row >> 10, h = col >> 6, d = col & (DH - 1);
                    ((unsigned short*)Out)[((size_t)(b * NH + h) * SEQ + s) * DH + d] = f2bf(v);
                } else {
                    if (f32) ((float*)Out)[(size_t)row * HID + col] = v;
                    else     ((unsigned short*)Out)[(size_t)row * HID + col] = f2bf(v);
                }
            }
        }
    }
}

// RSE attention, fp32 logit path. 1 wave = 64 queries of one (b,h).
__global__ __launch_bounds__(64) void attn_kernel(
    float* Qio,                             // (B*H, S, D) fp32 Q in; bf16 O out
    const float* __restrict__ Kt,           // (B*H, S, D) fp32
    const unsigned short* __restrict__ V,   // (B*H, S, D) bf16
    const void* __restrict__ lam_p,
    const unsigned int* __restrict__ flag)
{
    const int lane = threadIdx.x;
    const int mb = blockIdx.x;
    const int bh = blockIdx.y;
    const bool f32 = (flag[0] != 0u);
    const float lam = loadf(lam_p, 0, f32);
    const int m = mb * 64 + lane;
    const float pos_q = (float)m;

    float* Qrow = Qio + ((size_t)bh * SEQ + m) * DH;
    float q[DH];
#pragma unroll
    for (int dd = 0; dd < 16; dd++) {
        float4v u = *(const float4v*)(Qrow + dd * 4);
#pragma unroll
        for (int e = 0; e < 4; e++) q[dd * 4 + e] = u[e];
    }
    float acc[DH];
#pragma unroll
    for (int d = 0; d < DH; d++) acc[d] = 0.f;
    float rem = 1.f, l_i = 0.f, m_i = -INFINITY;

    const int jrow  = lane >> 2;
    const int dbase = (lane & 3) * 16;

    for (int kb = 0; kb < SEQ / 32; kb++) {
        float consumed = 0.f;
        float mblk = -INFINITY;
#pragma unroll
        for (int half = 0; half < 2; half++) {
            const int krow = kb * 32 + half * 16 + jrow;
            const float* Kp = Kt + ((size_t)bh * SEQ + krow) * DH + dbase;
            const unsigned short* Vp = V + ((size_t)bh * SEQ + krow) * DH + dbase;
            float kreg[16], vreg[16];
            {
#pragma unroll
                for (int c4 = 0; c4 < 4; c4++) {
                    float4v u = *(const float4v*)(Kp + c4 * 4);
#pragma unroll
                    for (int e = 0; e < 4; e++) kreg[c4 * 4 + e] = u[e];
                }
                ushort8 w0 = *(const ushort8*)(Vp);
                ushort8 w1 = *(const ushort8*)(Vp + 8);
#pragma unroll
                for (int e = 0; e < 8; e++) { vreg[e] = bf2f(w0[e]); vreg[8 + e] = bf2f(w1[e]); }
            }
#pragma unroll 1
            for (int j = 0; j < 16; j++) {
                const int srcbase = j * 4;
                float dot = 0.f;
#pragma unroll
                for (int d = 0; d < DH; d++) {
                    float kv = __int_as_float(__builtin_amdgcn_readlane(
                        __float_as_int(kreg[d & 15]), srcbase + (d >> 4)));
                    dot = fmaf(q[d], kv, dot);
                }
                const float pos_k = (float)(kb * 32 + half * 16 + j);
                const float logit = dot - lam * fabsf(pos_q - pos_k);
                mblk = fmaxf(mblk, logit);
                const float z = fminf(fmaxf(logit, -20.f), 20.f);
                const float beta = 1.f / (1.f + __expf(-z));
                const float w = beta * rem;
                consumed += w;
#pragma unroll
                for (int d = 0; d < DH; d++) {
                    float vv = __int_as_float(__builtin_amdgcn_readlane(
                        __float_as_int(vreg[d & 15]), srcbase + (d >> 4)));
                    acc[d] = fmaf(w, vv, acc[d]);
                }
            }
        }
        rem = fmaxf(rem * (1.f - consumed), 1e-6f);
        const float m_new = fmaxf(m_i, mblk);
        const float alpha = exp2f(m_i - m_new);
        l_i = l_i * alpha + consumed;
        m_i = m_new;
    }
    const float inv = 1.f / fmaxf(l_i, 1e-6f);
    unsigned short* Orow = (unsigned short*)Qrow;  // bf16 O packed at row head
#pragma unroll
    for (int dd = 0; dd < 8; dd++) {
        ushort8 u;
#pragma unroll
        for (int e = 0; e < 8; e++) u[e] = f2bf(acc[dd * 8 + e] * inv);
        *(ushort8*)(Orow + dd * 8) = u;
    }
}

extern "C" void kernel_launch(void* const* d_in, const int* in_sizes, int n_in,
                              void* d_out, int out_size, void* d_ws, size_t ws_size,
                              hipStream_t stream) {
    const void* x    = d_in[0];
    const void* Wq   = d_in[1];
    const void* bq   = d_in[2];
    const void* Wk   = d_in[3];
    const void* bk   = d_in[4];
    const void* Wv   = d_in[5];
    const void* bv   = d_in[6];
    const void* Wo   = d_in[7];
    const void* bo   = d_in[8];
    const void* lam  = d_in[9];
    const void* cosc = d_in[10];
    const void* sinc = d_in[11];

    const size_t NELEM = (size_t)MTOT * HID;
    unsigned int* flag = (unsigned int*)d_ws;
    float* Qf = (float*)((char*)d_ws + 64);                 // 50.33 MB fp32
    unsigned short* Vb = (unsigned short*)(Qf + NELEM);     // 25.17 MB bf16
    float* Kf = (float*)d_out;                              // 50.33 MB fp32, dead
                                                            // before final GEMM

    detect_kernel<<<1, 256, 0, stream>>>((const unsigned short*)x, flag);

    dim3 gg(MTOT / 128, HID / 128), gb(256);
    gemm_nt<0><<<gg, gb, 0, stream>>>(x, Wq, bq, cosc, sinc, flag, Qf);
    gemm_nt<1><<<gg, gb, 0, stream>>>(x, Wk, bk, cosc, sinc, flag, Kf);
    gemm_nt<2><<<gg, gb, 0, stream>>>(x, Wv, bv, cosc, sinc, flag, Vb);
    attn_kernel<<<dim3(SEQ / 64, BATCH * NH), 64, 0, stream>>>(Qf, Kf, Vb, lam, flag);
    gemm_nt<3><<<gg, gb, 0, stream>>>(Qf, Wo, bo, nullptr, nullptr, flag, d_out);
}

// Round 6
// 989.436 us; speedup vs baseline: 2.9357x; 2.9357x over previous
//
#include <hip/hip_runtime.h>
#include <math.h>

#define NH    12
#define SEQ   1024
#define DH    64
#define HID   768
#define BATCH 16
#define MTOT  (BATCH*SEQ)   // 16384
#define KDIM  HID           // 768
#define PSTRIDE 40          // LDS P row stride in bf16 (80B: 16B-aligned rows)

typedef __attribute__((ext_vector_type(8))) short short8;
typedef __attribute__((ext_vector_type(4))) short short4v;
typedef __attribute__((ext_vector_type(8))) unsigned short ushort8;
typedef __attribute__((ext_vector_type(4))) float float4v;

__device__ __forceinline__ float bf2f(unsigned short u) {
    union { unsigned int i; float f; } v; v.i = ((unsigned int)u) << 16; return v.f;
}
__device__ __forceinline__ unsigned short f2bf(float f) {
    union { float f; unsigned int i; } v; v.f = f;
    unsigned int x = v.i;
    return (unsigned short)((x + 0x7FFFu + ((x >> 16) & 1u)) >> 16);  // RNE
}
__device__ __forceinline__ float loadf(const void* p, size_t i, bool f32) {
    return f32 ? ((const float*)p)[i] : bf2f(((const unsigned short*)p)[i]);
}
template<bool F32>
__device__ __forceinline__ short8 load8(const void* p, size_t i) {
    if constexpr (F32) {
        const float* fp = (const float*)p + i;
        float4v f0 = *(const float4v*)fp, f1 = *(const float4v*)(fp + 4);
        short8 r;
#pragma unroll
        for (int e = 0; e < 4; e++) { r[e] = (short)f2bf(f0[e]); r[4 + e] = (short)f2bf(f1[e]); }
        return r;
    } else {
        return *(const short8*)((const unsigned short*)p + i);
    }
}
// Ootomo split with vector loads: f = hi + lo, hi = bf16(f), lo = bf16(f - hi).
template<bool F32>
__device__ __forceinline__ void load8_split(const void* p, size_t i,
                                            short8& hi, short8& lo) {
    if constexpr (F32) {
        const float* fp = (const float*)p + i;
        float4v f0 = *(const float4v*)fp, f1 = *(const float4v*)(fp + 4);
#pragma unroll
        for (int e = 0; e < 4; e++) {
            unsigned short h0 = f2bf(f0[e]), h1 = f2bf(f1[e]);
            hi[e] = (short)h0; hi[4 + e] = (short)h1;
            lo[e] = (short)f2bf(f0[e] - bf2f(h0));
            lo[4 + e] = (short)f2bf(f1[e] - bf2f(h1));
        }
    } else {
        hi = *(const short8*)((const unsigned short*)p + i);
#pragma unroll
        for (int e = 0; e < 8; e++) lo[e] = 0;
    }
}

// Runtime dtype classifier for x (flag=1 => fp32 inputs).
__global__ __launch_bounds__(256) void detect_kernel(
    const unsigned short* __restrict__ x, unsigned int* __restrict__ flag)
{
    __shared__ int cnt[256];
    const int tid = threadIdx.x;
    int local = 0;
    for (int i = tid; i < 1024; i += 256) {
        const unsigned short u = x[i];
        const int e = (u >> 7) & 0xFF;
        if ((e >= 96 && e <= 134) || ((u & 0x7FFF) == 0)) local++;
    }
    cnt[tid] = local;
    __syncthreads();
    for (int s = 128; s > 0; s >>= 1) {
        if (tid < s) cnt[tid] += cnt[tid + s];
        __syncthreads();
    }
    if (tid == 0) flag[0] = (cnt[0] < 900) ? 1u : 0u;
}

// Plain single-bf16 core: C = A@W^T, A row-major (M,K), W row-major (N,K).
template<bool AF32, bool BF32>
__device__ __forceinline__ void gemm_core(
    const void* __restrict__ A, const void* __restrict__ W,
    int m_blk, int n_blk, int l16, int quad, float4v acc[4][4])
{
    for (int k0 = 0; k0 < KDIM; k0 += 32) {
        const int kk = quad * 8 + k0;
        short8 a[4], b[4];
#pragma unroll
        for (int im = 0; im < 4; im++)
            a[im] = load8<AF32>(A, (size_t)(m_blk + im * 16 + l16) * KDIM + kk);
#pragma unroll
        for (int in = 0; in < 4; in++)
            b[in] = load8<BF32>(W, (size_t)(n_blk + in * 16 + l16) * KDIM + kk);
#pragma unroll
        for (int im = 0; im < 4; im++)
#pragma unroll
            for (int in = 0; in < 4; in++)
                acc[im][in] = __builtin_amdgcn_mfma_f32_16x16x32_bf16(
                    a[im], b[in], acc[im][in], 0, 0, 0);
    }
}

// Precise bf16x3 core (Q/K projections): rel err ~2^-17 — the RSE rem-cascade
// amplifies logit noise ~100x at the tail, single-bf16 fails the 2% bound.
template<bool F32>
__device__ __forceinline__ void gemm_core_precise(
    const void* __restrict__ A, const void* __restrict__ W,
    int m_blk, int n_blk, int l16, int quad, float4v acc[4][4])
{
    for (int k0 = 0; k0 < KDIM; k0 += 32) {
        const int kk = quad * 8 + k0;
        short8 ah[4], al[4], bh[4], bl[4];
#pragma unroll
        for (int im = 0; im < 4; im++)
            load8_split<F32>(A, (size_t)(m_blk + im * 16 + l16) * KDIM + kk, ah[im], al[im]);
#pragma unroll
        for (int in = 0; in < 4; in++)
            load8_split<F32>(W, (size_t)(n_blk + in * 16 + l16) * KDIM + kk, bh[in], bl[in]);
#pragma unroll
        for (int im = 0; im < 4; im++)
#pragma unroll
            for (int in = 0; in < 4; in++) {
                acc[im][in] = __builtin_amdgcn_mfma_f32_16x16x32_bf16(
                    ah[im], bh[in], acc[im][in], 0, 0, 0);
                acc[im][in] = __builtin_amdgcn_mfma_f32_16x16x32_bf16(
                    al[im], bh[in], acc[im][in], 0, 0, 0);
                acc[im][in] = __builtin_amdgcn_mfma_f32_16x16x32_bf16(
                    ah[im], bl[in], acc[im][in], 0, 0, 0);
            }
    }
}

// MODE 0: precise, +bias +rope *0.125 -> hi/lo bf16 (B,H,S,D)  (Q)
// MODE 1: precise, +bias +rope        -> hi/lo bf16 (B,H,S,D)  (K)
// MODE 2: fast,    +bias              -> bf16 V^T (B,H,D,S)
// MODE 3: fast,    +bias              -> d_out (M,N), dtype per flag
template<int MODE>
__global__ __launch_bounds__(256) void gemm_nt(
    const void* __restrict__ A, const void* __restrict__ W,
    const void* __restrict__ bias, const void* __restrict__ cosc,
    const void* __restrict__ sinc, const unsigned int* __restrict__ flag,
    void* __restrict__ Out, void* __restrict__ Out2)
{
    const int tid  = threadIdx.x;
    const int wid  = tid >> 6;
    const int lane = tid & 63;
    const int quad = lane >> 4;
    const int l16  = lane & 15;
    const int m_blk = blockIdx.x * 128 + (wid >> 1) * 64;
    const int n_blk = blockIdx.y * 128 + (wid & 1) * 64;
    const bool f32 = (flag[0] != 0u);

    float4v acc[4][4];
#pragma unroll
    for (int i = 0; i < 4; i++)
#pragma unroll
        for (int j = 0; j < 4; j++) acc[i][j] = (float4v)(0.f);

    if constexpr (MODE <= 1) {
        if (f32) gemm_core_precise<true >(A, W, m_blk, n_blk, l16, quad, acc);
        else     gemm_core_precise<false>(A, W, m_blk, n_blk, l16, quad, acc);
    } else if constexpr (MODE == 3) {
        if (f32) gemm_core<false, true >(A, W, m_blk, n_blk, l16, quad, acc);
        else     gemm_core<false, false>(A, W, m_blk, n_blk, l16, quad, acc);
    } else {
        if (f32) gemm_core<true,  true >(A, W, m_blk, n_blk, l16, quad, acc);
        else     gemm_core<false, false>(A, W, m_blk, n_blk, l16, quad, acc);
    }

#pragma unroll
    for (int im = 0; im < 4; im++) {
#pragma unroll
        for (int in = 0; in < 4; in++) {
            const int col = n_blk + in * 16 + l16;
            const float bval = loadf(bias, col, f32);
            if constexpr (MODE == 2) {
                // pack 4 consecutive s into one b64 store of V^T
                short4v pk;
#pragma unroll
                for (int r = 0; r < 4; r++)
                    pk[r] = (short)f2bf(acc[im][in][r] + bval);
                const int row = m_blk + im * 16 + quad * 4;
                const int b = row >> 10, s = row & (SEQ - 1);
                const int h = col >> 6, d = col & (DH - 1);
                *(short4v*)((unsigned short*)Out +
                    ((size_t)(b * NH + h) * DH + d) * SEQ + s) = pk;
            } else {
#pragma unroll
                for (int r = 0; r < 4; r++) {
                    const int row = m_blk + im * 16 + quad * 4 + r;
                    float v = acc[im][in][r] + bval;
                    if constexpr (MODE <= 1) {
                        const int s  = row & (SEQ - 1);
                        const int d  = col & (DH - 1);
                        const int d2 = d >> 1;
                        const float c  = loadf(cosc, s * (DH / 2) + d2, f32);
                        const float sn = loadf(sinc, s * (DH / 2) + d2, f32);
                        const float p = __shfl_xor(v, 1);  // lane^1 <-> d^1
                        float o = (d & 1) ? (v * c + p * sn) : (v * c - p * sn);
                        if (MODE == 0) o *= 0.125f;
                        const int b = row >> 10, h = col >> 6;
                        const size_t idx = ((size_t)(b * NH + h) * SEQ + s) * DH + d;
                        const unsigned short hbits = f2bf(o);
                        ((unsigned short*)Out)[idx]  = hbits;
                        ((unsigned short*)Out2)[idx] = f2bf(o - bf2f(hbits));
                    } else {
                        if (f32) ((float*)Out)[(size_t)row * HID + col] = v;
                        else     ((unsigned short*)Out)[(size_t)row * HID + col] = f2bf(v);
                    }
                }
            }
        }
    }
}

// MFMA RSE attention. 1 wave = 64 queries of one (b,h); sequential 32-key
// chunks (rem carry). S^T = K·Q^T via bf16x3 MFMA (queries in C-layout
// columns -> per-query stats need only 2 cross-quad shfl_xor). P^T -> LDS ->
// B-operand of O^T = V^T·P^T.
__global__ __launch_bounds__(64, 2) void attn_mfma(
    const unsigned short* __restrict__ Qhi, const unsigned short* __restrict__ Qlo,
    const unsigned short* __restrict__ Khi, const unsigned short* __restrict__ Klo,
    const unsigned short* __restrict__ Vt,   // (B*H, D, S) bf16
    const void* __restrict__ lam_p, const unsigned int* __restrict__ flag,
    unsigned short* __restrict__ ctx)        // (B, S, HID) bf16
{
    const int lane = threadIdx.x;
    const int quad = lane >> 4;
    const int l16  = lane & 15;
    const int mb = blockIdx.x;      // 16 query tiles of 64
    const int bh = blockIdx.y;
    const bool f32 = (flag[0] != 0u);
    const float lam = loadf(lam_p, 0, f32);

    __shared__ unsigned short Plds[64 * PSTRIDE];  // P^T as [q][key_local]

    // Q fragments (B-operand), resident: [qn][kstep], hi+lo
    short8 qh[4][2], ql[4][2];
#pragma unroll
    for (int qn = 0; qn < 4; qn++)
#pragma unroll
        for (int ks = 0; ks < 2; ks++) {
            const size_t base = ((size_t)bh * SEQ + (mb * 64 + qn * 16 + l16)) * DH
                                + ks * 32 + quad * 8;
            qh[qn][ks] = *(const short8*)(Qhi + base);
            ql[qn][ks] = *(const short8*)(Qlo + base);
        }

    float4v acc_o[4][4];   // O^T tiles [dt][jn]
#pragma unroll
    for (int i = 0; i < 4; i++)
#pragma unroll
        for (int j = 0; j < 4; j++) acc_o[i][j] = (float4v)(0.f);

    float rem[4] = {1.f, 1.f, 1.f, 1.f};
    float l_i[4] = {0.f, 0.f, 0.f, 0.f};
    float m_i[4] = {-INFINITY, -INFINITY, -INFINITY, -INFINITY};
    float qf[4];
#pragma unroll
    for (int qn = 0; qn < 4; qn++) qf[qn] = (float)(mb * 64 + qn * 16 + l16);

    for (int kb = 0; kb < SEQ / 32; kb++) {
        // ---- S^T = K·Q^T (bf16x3) ----
        short8 kh[2][2], kl[2][2];
#pragma unroll
        for (int kt = 0; kt < 2; kt++)
#pragma unroll
            for (int ks = 0; ks < 2; ks++) {
                const size_t base = ((size_t)bh * SEQ + (kb * 32 + kt * 16 + l16)) * DH
                                    + ks * 32 + quad * 8;
                kh[kt][ks] = *(const short8*)(Khi + base);
                kl[kt][ks] = *(const short8*)(Klo + base);
            }
        float4v s[2][4];
#pragma unroll
        for (int kt = 0; kt < 2; kt++)
#pragma unroll
            for (int qn = 0; qn < 4; qn++) s[kt][qn] = (float4v)(0.f);
#pragma unroll
        for (int ks = 0; ks < 2; ks++)
#pragma unroll
            for (int kt = 0; kt < 2; kt++)
#pragma unroll
                for (int qn = 0; qn < 4; qn++) {
                    s[kt][qn] = __builtin_amdgcn_mfma_f32_16x16x32_bf16(
                        kh[kt][ks], qh[qn][ks], s[kt][qn], 0, 0, 0);
                    s[kt][qn] = __builtin_amdgcn_mfma_f32_16x16x32_bf16(
                        kl[kt][ks], qh[qn][ks], s[kt][qn], 0, 0, 0);
                    s[kt][qn] = __builtin_amdgcn_mfma_f32_16x16x32_bf16(
                        kh[kt][ks], ql[qn][ks], s[kt][qn], 0, 0, 0);
                }

        // ---- sigmoid / decay / stats (w overwrites s in place) ----
        float cons[4], mx[4];
#pragma unroll
        for (int qn = 0; qn < 4; qn++) { cons[qn] = 0.f; mx[qn] = -INFINITY; }
#pragma unroll
        for (int kt = 0; kt < 2; kt++)
#pragma unroll
            for (int qn = 0; qn < 4; qn++)
#pragma unroll
                for (int r = 0; r < 4; r++) {
                    const float keyf = (float)(kb * 32 + kt * 16 + quad * 4 + r);
                    const float logit = s[kt][qn][r] - lam * fabsf(qf[qn] - keyf);
                    mx[qn] = fmaxf(mx[qn], logit);
                    const float z = fminf(fmaxf(logit, -20.f), 20.f);
                    const float beta = __builtin_amdgcn_rcpf(
                        1.f + exp2f(-z * 1.44269504088896f));
                    const float w = beta * rem[qn];
                    cons[qn] += w;
                    s[kt][qn][r] = w;
                }
#pragma unroll
        for (int qn = 0; qn < 4; qn++) {
            cons[qn] += __shfl_xor(cons[qn], 16);
            cons[qn] += __shfl_xor(cons[qn], 32);
            mx[qn] = fmaxf(mx[qn], __shfl_xor(mx[qn], 16));
            mx[qn] = fmaxf(mx[qn], __shfl_xor(mx[qn], 32));
        }

        // ---- pack P^T to LDS ----
#pragma unroll
        for (int kt = 0; kt < 2; kt++)
#pragma unroll
            for (int qn = 0; qn < 4; qn++) {
                short4v pk;
#pragma unroll
                for (int r = 0; r < 4; r++) pk[r] = (short)f2bf(s[kt][qn][r]);
                *(short4v*)(Plds + (qn * 16 + l16) * PSTRIDE + kt * 16 + quad * 4) = pk;
            }
        __syncthreads();

        // ---- O^T += V^T·P^T ----
        short8 vf[4], pf[4];
#pragma unroll
        for (int dt = 0; dt < 4; dt++)
            vf[dt] = *(const short8*)(Vt + ((size_t)bh * DH + dt * 16 + l16) * SEQ
                                      + kb * 32 + quad * 8);
#pragma unroll
        for (int jn = 0; jn < 4; jn++)
            pf[jn] = *(const short8*)(Plds + (jn * 16 + l16) * PSTRIDE + quad * 8);
#pragma unroll
        for (int dt = 0; dt < 4; dt++)
#pragma unroll
            for (int jn = 0; jn < 4; jn++)
                acc_o[dt][jn] = __builtin_amdgcn_mfma_f32_16x16x32_bf16(
                    vf[dt], pf[jn], acc_o[dt][jn], 0, 0, 0);
        __syncthreads();

        // ---- state update (after w used this block's rem) ----
#pragma unroll
        for (int qn = 0; qn < 4; qn++) {
            rem[qn] = fmaxf(rem[qn] * (1.f - cons[qn]), 1e-6f);
            const float m_new = fmaxf(m_i[qn], mx[qn]);
            const float alpha = exp2f(m_i[qn] - m_new);
            l_i[qn] = l_i[qn] * alpha + cons[qn];
            m_i[qn] = m_new;
        }
    }

    // ---- epilogue: O^T / l, store ctx (B,S,HID) ----
    const int b = bh / NH, h = bh % NH;
    float inv[4];
#pragma unroll
    for (int jn = 0; jn < 4; jn++)
        inv[jn] = __builtin_amdgcn_rcpf(fmaxf(l_i[jn], 1e-6f));
#pragma unroll
    for (int dt = 0; dt < 4; dt++)
#pragma unroll
        for (int jn = 0; jn < 4; jn++) {
            short4v pk;
#pragma unroll
            for (int r = 0; r < 4; r++)
                pk[r] = (short)f2bf(acc_o[dt][jn][r] * inv[jn]);
            const int q_g = mb * 64 + jn * 16 + l16;
            *(short4v*)(ctx + ((size_t)(b * SEQ + q_g) * HID
                               + h * DH + dt * 16 + quad * 4)) = pk;
        }
}

extern "C" void kernel_launch(void* const* d_in, const int* in_sizes, int n_in,
                              void* d_out, int out_size, void* d_ws, size_t ws_size,
                              hipStream_t stream) {
    const void* x    = d_in[0];
    const void* Wq   = d_in[1];
    const void* bq   = d_in[2];
    const void* Wk   = d_in[3];
    const void* bk   = d_in[4];
    const void* Wv   = d_in[5];
    const void* bv   = d_in[6];
    const void* Wo   = d_in[7];
    const void* bo   = d_in[8];
    const void* lam  = d_in[9];
    const void* cosc = d_in[10];
    const void* sinc = d_in[11];

    const size_t NELEM = (size_t)MTOT * HID;  // 12.58M
    unsigned int* flag = (unsigned int*)d_ws;
    unsigned short* Qhi = (unsigned short*)((char*)d_ws + 64);
    unsigned short* Qlo = Qhi + NELEM;
    unsigned short* Vt  = Qlo + NELEM;
    unsigned short* Ctx = Vt + NELEM;
    // ws: 64 + 4*25.17MB = 100.7MB (R1-proven available)
    unsigned short* Khi = (unsigned short*)d_out;   // d_out = 50.33MB, dead
    unsigned short* Klo = Khi + NELEM;              // before final GEMM

    detect_kernel<<<1, 256, 0, stream>>>((const unsigned short*)x, flag);

    dim3 gg(MTOT / 128, HID / 128), gb(256);
    gemm_nt<0><<<gg, gb, 0, stream>>>(x, Wq, bq, cosc, sinc, flag, Qhi, Qlo);
    gemm_nt<1><<<gg, gb, 0, stream>>>(x, Wk, bk, cosc, sinc, flag, Khi, Klo);
    gemm_nt<2><<<gg, gb, 0, stream>>>(x, Wv, bv, cosc, sinc, flag, Vt, nullptr);
    attn_mfma<<<dim3(SEQ / 64, BATCH * NH), 64, 0, stream>>>(
        Qhi, Qlo, Khi, Klo, Vt, lam, flag, Ctx);
    gemm_nt<3><<<gg, gb, 0, stream>>>(Ctx, Wo, bo, nullptr, nullptr, flag, d_out, nullptr);
}

// Round 7
// 836.632 us; speedup vs baseline: 3.4719x; 1.1826x over previous
//
#include <hip/hip_runtime.h>
#include <math.h>

#define NH    12
#define SEQ   1024
#define DH    64
#define HID   768
#define BATCH 16
#define MTOT  (BATCH*SEQ)   // 16384
#define KDIM  HID           // 768
#define PSTRIDE 40          // attn LDS P row stride (80B, 16B-aligned)

typedef __attribute__((ext_vector_type(8))) short short8;
typedef __attribute__((ext_vector_type(4))) short short4v;
typedef __attribute__((ext_vector_type(8))) unsigned short ushort8;
typedef __attribute__((ext_vector_type(4))) float float4v;

__device__ __forceinline__ float bf2f(unsigned short u) {
    union { unsigned int i; float f; } v; v.i = ((unsigned int)u) << 16; return v.f;
}
__device__ __forceinline__ unsigned short f2bf(float f) {
    union { float f; unsigned int i; } v; v.f = f;
    unsigned int x = v.i;
    return (unsigned short)((x + 0x7FFFu + ((x >> 16) & 1u)) >> 16);  // RNE
}
__device__ __forceinline__ float loadf(const void* p, size_t i, bool f32) {
    return f32 ? ((const float*)p)[i] : bf2f(((const unsigned short*)p)[i]);
}

// async global->LDS, 16B per lane (m97 lever). LDS dest must be
// wave-uniform base + lane*16 — our chunk mapping guarantees it.
__device__ __forceinline__ void gload_lds16(const void* g, void* l) {
    __builtin_amdgcn_global_load_lds(
        (const __attribute__((address_space(1))) unsigned int*)g,
        (__attribute__((address_space(3))) unsigned int*)l, 16, 0, 0);
}

// Runtime dtype classifier for x (flag=1 => fp32 inputs).
__global__ __launch_bounds__(256) void detect_kernel(
    const unsigned short* __restrict__ x, unsigned int* __restrict__ flag)
{
    __shared__ int cnt[256];
    const int tid = threadIdx.x;
    int local = 0;
    for (int i = tid; i < 1024; i += 256) {
        const unsigned short u = x[i];
        const int e = (u >> 7) & 0xFF;
        if ((e >= 96 && e <= 134) || ((u & 0x7FFF) == 0)) local++;
    }
    cnt[tid] = local;
    __syncthreads();
    for (int s = 128; s > 0; s >>= 1) {
        if (tid < s) cnt[tid] += cnt[tid + s];
        __syncthreads();
    }
    if (tid == 0) flag[0] = (cnt[0] < 900) ? 1u : 0u;
}

// x -> xhi + xlo (Ootomo split), 8 elems/thread, memory-bound.
__global__ __launch_bounds__(256) void split_x(
    const void* __restrict__ x, const unsigned int* __restrict__ flag,
    unsigned short* __restrict__ hi, unsigned short* __restrict__ lo)
{
    const size_t i = ((size_t)blockIdx.x * 256 + threadIdx.x) * 8;
    if (i >= (size_t)MTOT * KDIM) return;
    ushort8 h, l;
    if (flag[0]) {
        const float* fp = (const float*)x + i;
        float4v f0 = *(const float4v*)fp, f1 = *(const float4v*)(fp + 4);
#pragma unroll
        for (int e = 0; e < 4; e++) {
            unsigned short h0 = f2bf(f0[e]), h1 = f2bf(f1[e]);
            h[e] = h0; h[4 + e] = h1;
            l[e] = f2bf(f0[e] - bf2f(h0));
            l[4 + e] = f2bf(f1[e] - bf2f(h1));
        }
    } else {
        h = *(const ushort8*)((const unsigned short*)x + i);
#pragma unroll
        for (int e = 0; e < 8; e++) l[e] = 0;
    }
    *(ushort8*)(hi + i) = h;
    *(ushort8*)(lo + i) = l;
}

// W fragment load with optional in-register split (W is L2-resident).
template<bool WF32, bool PRECISE>
__device__ __forceinline__ void loadW(const void* __restrict__ W, size_t idx,
                                      short8& hi, short8& lo) {
    if constexpr (WF32) {
        const float* fp = (const float*)W + idx;
        float4v f0 = *(const float4v*)fp, f1 = *(const float4v*)(fp + 4);
#pragma unroll
        for (int e = 0; e < 4; e++) {
            unsigned short h0 = f2bf(f0[e]), h1 = f2bf(f1[e]);
            hi[e] = (short)h0; hi[4 + e] = (short)h1;
            if constexpr (PRECISE) {
                lo[e] = (short)f2bf(f0[e] - bf2f(h0));
                lo[4 + e] = (short)f2bf(f1[e] - bf2f(h1));
            }
        }
    } else {
        hi = *(const short8*)((const unsigned short*)W + idx);
        if constexpr (PRECISE) {
#pragma unroll
            for (int e = 0; e < 8; e++) lo[e] = 0;
        }
    }
}

// K-loop: A staged via global_load_lds (bf16, pre-split), B direct-global.
template<bool PRECISE, bool WF32>
__device__ __forceinline__ void staged_kloop(
    const unsigned short* __restrict__ Ahi, const unsigned short* __restrict__ Alo,
    const void* __restrict__ W,
    unsigned short* sAhi, unsigned short* sAlo,
    int m_blk0, int n_base, int wid, int lane, float4v acc[4][4])
{
    const int tid  = wid * 64 + lane;
    const int quad = lane >> 4, l16 = lane & 15;
    const int m_off = (wid >> 1) * 64;
    const int srow = tid >> 2;   // staging row 0..63
    const int scc  = tid & 3;    // 16B chunk within 32-elem row

    for (int k0 = 0; k0 < KDIM; k0 += 32) {
        // ---- stage A tiles (async, no VGPR round-trip) ----
#pragma unroll
        for (int it = 0; it < 2; it++) {
            const int r = it * 64 + srow;
            const size_t gidx = (size_t)(m_blk0 + r) * KDIM + k0 + scc * 8;
            const int loff = r * 32 + scc * 8;
            gload_lds16(Ahi + gidx, sAhi + loff);
            if constexpr (PRECISE) gload_lds16(Alo + gidx, sAlo + loff);
        }
        // ---- B fragments (L2-hot W) ----
        short8 bh[4], bl[4];
#pragma unroll
        for (int in = 0; in < 4; in++)
            loadW<WF32, PRECISE>(W, (size_t)(n_base + in * 16 + l16) * KDIM + k0 + quad * 8,
                                 bh[in], bl[in]);
        __syncthreads();
        // ---- A fragments from LDS ----
        short8 ah[4], al[4];
#pragma unroll
        for (int im = 0; im < 4; im++) {
            const int r = m_off + im * 16 + l16;
            ah[im] = *(const short8*)(sAhi + r * 32 + quad * 8);
            if constexpr (PRECISE) al[im] = *(const short8*)(sAlo + r * 32 + quad * 8);
        }
        // ---- MFMA ----
#pragma unroll
        for (int im = 0; im < 4; im++)
#pragma unroll
            for (int in = 0; in < 4; in++) {
                acc[im][in] = __builtin_amdgcn_mfma_f32_16x16x32_bf16(
                    ah[im], bh[in], acc[im][in], 0, 0, 0);
                if constexpr (PRECISE) {
                    acc[im][in] = __builtin_amdgcn_mfma_f32_16x16x32_bf16(
                        al[im], bh[in], acc[im][in], 0, 0, 0);
                    acc[im][in] = __builtin_amdgcn_mfma_f32_16x16x32_bf16(
                        ah[im], bl[in], acc[im][in], 0, 0, 0);
                }
            }
        __syncthreads();
    }
}

// MODE 0: precise, +bias +rope *0.125 -> hi/lo bf16 (B,H,S,D)  (Q)
// MODE 1: precise, +bias +rope        -> hi/lo bf16 (B,H,S,D)  (K)
// MODE 2: fast,    +bias              -> bf16 V^T (B,H,D,S)
// MODE 3: fast,    +bias              -> d_out (M,N), dtype per flag
template<int MODE>
__global__ __launch_bounds__(256) void gemm_staged(
    const unsigned short* __restrict__ Ahi, const unsigned short* __restrict__ Alo,
    const void* __restrict__ W, const void* __restrict__ bias,
    const void* __restrict__ cosc, const void* __restrict__ sinc,
    const unsigned int* __restrict__ flag,
    void* __restrict__ Out, void* __restrict__ Out2)
{
    constexpr bool PRECISE = (MODE <= 1);
    __shared__ unsigned short sAhi[128 * 32];
    __shared__ unsigned short sAlo[PRECISE ? 128 * 32 : 64];

    const int tid  = threadIdx.x;
    const int wid  = tid >> 6;
    const int lane = tid & 63;
    const int quad = lane >> 4;
    const int l16  = lane & 15;
    const int m_blk0 = blockIdx.x * 128;
    const int m_blk = m_blk0 + (wid >> 1) * 64;
    const int n_base = blockIdx.y * 128 + (wid & 1) * 64;
    const bool f32 = (flag[0] != 0u);

    float4v acc[4][4];
#pragma unroll
    for (int i = 0; i < 4; i++)
#pragma unroll
        for (int j = 0; j < 4; j++) acc[i][j] = (float4v)(0.f);

    if (f32) staged_kloop<PRECISE, true >(Ahi, Alo, W, sAhi, sAlo, m_blk0, n_base, wid, lane, acc);
    else     staged_kloop<PRECISE, false>(Ahi, Alo, W, sAhi, sAlo, m_blk0, n_base, wid, lane, acc);

#pragma unroll
    for (int im = 0; im < 4; im++) {
#pragma unroll
        for (int in = 0; in < 4; in++) {
            const int col = n_base + in * 16 + l16;
            const float bval = loadf(bias, col, f32);
            if constexpr (MODE == 2) {
                short4v pk;
#pragma unroll
                for (int r = 0; r < 4; r++)
                    pk[r] = (short)f2bf(acc[im][in][r] + bval);
                const int row = m_blk + im * 16 + quad * 4;
                const int b = row >> 10, s = row & (SEQ - 1);
                const int h = col >> 6, d = col & (DH - 1);
                *(short4v*)((unsigned short*)Out +
                    ((size_t)(b * NH + h) * DH + d) * SEQ + s) = pk;
            } else {
#pragma unroll
                for (int r = 0; r < 4; r++) {
                    const int row = m_blk + im * 16 + quad * 4 + r;
                    float v = acc[im][in][r] + bval;
                    if constexpr (MODE <= 1) {
                        const int s  = row & (SEQ - 1);
                        const int d  = col & (DH - 1);
                        const int d2 = d >> 1;
                        const float c  = loadf(cosc, s * (DH / 2) + d2, f32);
                        const float sn = loadf(sinc, s * (DH / 2) + d2, f32);
                        const float p = __shfl_xor(v, 1);  // lane^1 <-> d^1
                        float o = (d & 1) ? (v * c + p * sn) : (v * c - p * sn);
                        if (MODE == 0) o *= 0.125f;
                        const int b = row >> 10, h = col >> 6;
                        const size_t idx = ((size_t)(b * NH + h) * SEQ + s) * DH + d;
                        const unsigned short hbits = f2bf(o);
                        ((unsigned short*)Out)[idx]  = hbits;
                        ((unsigned short*)Out2)[idx] = f2bf(o - bf2f(hbits));
                    } else {
                        if (f32) ((float*)Out)[(size_t)row * HID + col] = v;
                        else     ((unsigned short*)Out)[(size_t)row * HID + col] = f2bf(v);
                    }
                }
            }
        }
    }
}

// MFMA RSE attention (unchanged from R6, correctness-proven).
__global__ __launch_bounds__(64, 2) void attn_mfma(
    const unsigned short* __restrict__ Qhi, const unsigned short* __restrict__ Qlo,
    const unsigned short* __restrict__ Khi, const unsigned short* __restrict__ Klo,
    const unsigned short* __restrict__ Vt,   // (B*H, D, S) bf16
    const void* __restrict__ lam_p, const unsigned int* __restrict__ flag,
    unsigned short* __restrict__ ctx)        // (B, S, HID) bf16
{
    const int lane = threadIdx.x;
    const int quad = lane >> 4;
    const int l16  = lane & 15;
    const int mb = blockIdx.x;
    const int bh = blockIdx.y;
    const bool f32 = (flag[0] != 0u);
    const float lam = loadf(lam_p, 0, f32);

    __shared__ unsigned short Plds[64 * PSTRIDE];

    short8 qh[4][2], ql[4][2];
#pragma unroll
    for (int qn = 0; qn < 4; qn++)
#pragma unroll
        for (int ks = 0; ks < 2; ks++) {
            const size_t base = ((size_t)bh * SEQ + (mb * 64 + qn * 16 + l16)) * DH
                                + ks * 32 + quad * 8;
            qh[qn][ks] = *(const short8*)(Qhi + base);
            ql[qn][ks] = *(const short8*)(Qlo + base);
        }

    float4v acc_o[4][4];
#pragma unroll
    for (int i = 0; i < 4; i++)
#pragma unroll
        for (int j = 0; j < 4; j++) acc_o[i][j] = (float4v)(0.f);

    float rem[4] = {1.f, 1.f, 1.f, 1.f};
    float l_i[4] = {0.f, 0.f, 0.f, 0.f};
    float m_i[4] = {-INFINITY, -INFINITY, -INFINITY, -INFINITY};
    float qf[4];
#pragma unroll
    for (int qn = 0; qn < 4; qn++) qf[qn] = (float)(mb * 64 + qn * 16 + l16);

    for (int kb = 0; kb < SEQ / 32; kb++) {
        short8 kh[2][2], kl[2][2];
#pragma unroll
        for (int kt = 0; kt < 2; kt++)
#pragma unroll
            for (int ks = 0; ks < 2; ks++) {
                const size_t base = ((size_t)bh * SEQ + (kb * 32 + kt * 16 + l16)) * DH
                                    + ks * 32 + quad * 8;
                kh[kt][ks] = *(const short8*)(Khi + base);
                kl[kt][ks] = *(const short8*)(Klo + base);
            }
        float4v s[2][4];
#pragma unroll
        for (int kt = 0; kt < 2; kt++)
#pragma unroll
            for (int qn = 0; qn < 4; qn++) s[kt][qn] = (float4v)(0.f);
#pragma unroll
        for (int ks = 0; ks < 2; ks++)
#pragma unroll
            for (int kt = 0; kt < 2; kt++)
#pragma unroll
                for (int qn = 0; qn < 4; qn++) {
                    s[kt][qn] = __builtin_amdgcn_mfma_f32_16x16x32_bf16(
                        kh[kt][ks], qh[qn][ks], s[kt][qn], 0, 0, 0);
                    s[kt][qn] = __builtin_amdgcn_mfma_f32_16x16x32_bf16(
                        kl[kt][ks], qh[qn][ks], s[kt][qn], 0, 0, 0);
                    s[kt][qn] = __builtin_amdgcn_mfma_f32_16x16x32_bf16(
                        kh[kt][ks], ql[qn][ks], s[kt][qn], 0, 0, 0);
                }

        float cons[4], mx[4];
#pragma unroll
        for (int qn = 0; qn < 4; qn++) { cons[qn] = 0.f; mx[qn] = -INFINITY; }
#pragma unroll
        for (int kt = 0; kt < 2; kt++)
#pragma unroll
            for (int qn = 0; qn < 4; qn++)
#pragma unroll
                for (int r = 0; r < 4; r++) {
                    const float keyf = (float)(kb * 32 + kt * 16 + quad * 4 + r);
                    const float logit = s[kt][qn][r] - lam * fabsf(qf[qn] - keyf);
                    mx[qn] = fmaxf(mx[qn], logit);
                    const float z = fminf(fmaxf(logit, -20.f), 20.f);
                    const float beta = __builtin_amdgcn_rcpf(
                        1.f + exp2f(-z * 1.44269504088896f));
                    const float w = beta * rem[qn];
                    cons[qn] += w;
                    s[kt][qn][r] = w;
                }
#pragma unroll
        for (int qn = 0; qn < 4; qn++) {
            cons[qn] += __shfl_xor(cons[qn], 16);
            cons[qn] += __shfl_xor(cons[qn], 32);
            mx[qn] = fmaxf(mx[qn], __shfl_xor(mx[qn], 16));
            mx[qn] = fmaxf(mx[qn], __shfl_xor(mx[qn], 32));
        }

#pragma unroll
        for (int kt = 0; kt < 2; kt++)
#pragma unroll
            for (int qn = 0; qn < 4; qn++) {
                short4v pk;
#pragma unroll
                for (int r = 0; r < 4; r++) pk[r] = (short)f2bf(s[kt][qn][r]);
                *(short4v*)(Plds + (qn * 16 + l16) * PSTRIDE + kt * 16 + quad * 4) = pk;
            }
        __syncthreads();

        short8 vf[4], pf[4];
#pragma unroll
        for (int dt = 0; dt < 4; dt++)
            vf[dt] = *(const short8*)(Vt + ((size_t)bh * DH + dt * 16 + l16) * SEQ
                                      + kb * 32 + quad * 8);
#pragma unroll
        for (int jn = 0; jn < 4; jn++)
            pf[jn] = *(const short8*)(Plds + (jn * 16 + l16) * PSTRIDE + quad * 8);
#pragma unroll
        for (int dt = 0; dt < 4; dt++)
#pragma unroll
            for (int jn = 0; jn < 4; jn++)
                acc_o[dt][jn] = __builtin_amdgcn_mfma_f32_16x16x32_bf16(
                    vf[dt], pf[jn], acc_o[dt][jn], 0, 0, 0);
        __syncthreads();

#pragma unroll
        for (int qn = 0; qn < 4; qn++) {
            rem[qn] = fmaxf(rem[qn] * (1.f - cons[qn]), 1e-6f);
            const float m_new = fmaxf(m_i[qn], mx[qn]);
            const float alpha = exp2f(m_i[qn] - m_new);
            l_i[qn] = l_i[qn] * alpha + cons[qn];
            m_i[qn] = m_new;
        }
    }

    const int b = bh / NH, h = bh % NH;
    float inv[4];
#pragma unroll
    for (int jn = 0; jn < 4; jn++)
        inv[jn] = __builtin_amdgcn_rcpf(fmaxf(l_i[jn], 1e-6f));
#pragma unroll
    for (int dt = 0; dt < 4; dt++)
#pragma unroll
        for (int jn = 0; jn < 4; jn++) {
            short4v pk;
#pragma unroll
            for (int r = 0; r < 4; r++)
                pk[r] = (short)f2bf(acc_o[dt][jn][r] * inv[jn]);
            const int q_g = mb * 64 + jn * 16 + l16;
            *(short4v*)(ctx + ((size_t)(b * SEQ + q_g) * HID
                               + h * DH + dt * 16 + quad * 4)) = pk;
        }
}

extern "C" void kernel_launch(void* const* d_in, const int* in_sizes, int n_in,
                              void* d_out, int out_size, void* d_ws, size_t ws_size,
                              hipStream_t stream) {
    const void* x    = d_in[0];
    const void* Wq   = d_in[1];
    const void* bq   = d_in[2];
    const void* Wk   = d_in[3];
    const void* bk   = d_in[4];
    const void* Wv   = d_in[5];
    const void* bv   = d_in[6];
    const void* Wo   = d_in[7];
    const void* bo   = d_in[8];
    const void* lam  = d_in[9];
    const void* cosc = d_in[10];
    const void* sinc = d_in[11];

    const size_t NELEM = (size_t)MTOT * HID;  // 12.58M
    unsigned int* flag = (unsigned int*)d_ws;
    unsigned short* Xhi = (unsigned short*)((char*)d_ws + 64);
    unsigned short* Xlo = Xhi + NELEM;   // becomes Vt after K GEMM
    unsigned short* Qhi = Xlo + NELEM;
    unsigned short* Qlo = Qhi + NELEM;
    // ws = 64 + 4*25.17MB = 100,663,424 B (exactly R6-proven usage)
    unsigned short* Vt  = Xlo;           // xlo dead after K GEMM
    unsigned short* Ctx = Xhi;           // xhi dead after V GEMM
    unsigned short* Khi = (unsigned short*)d_out;  // dead before final GEMM
    unsigned short* Klo = Khi + NELEM;

    detect_kernel<<<1, 256, 0, stream>>>((const unsigned short*)x, flag);
    split_x<<<(MTOT * KDIM) / (256 * 8), 256, 0, stream>>>(x, flag, Xhi, Xlo);

    dim3 gg(MTOT / 128, HID / 128), gb(256);
    gemm_staged<0><<<gg, gb, 0, stream>>>(Xhi, Xlo, Wq, bq, cosc, sinc, flag, Qhi, Qlo);
    gemm_staged<1><<<gg, gb, 0, stream>>>(Xhi, Xlo, Wk, bk, cosc, sinc, flag, Khi, Klo);
    gemm_staged<2><<<gg, gb, 0, stream>>>(Xhi, nullptr, Wv, bv, nullptr, nullptr, flag, Vt, nullptr);
    attn_mfma<<<dim3(SEQ / 64, BATCH * NH), 64, 0, stream>>>(
        Qhi, Qlo, Khi, Klo, Vt, lam, flag, Ctx);
    gemm_staged<3><<<gg, gb, 0, stream>>>(Ctx, nullptr, Wo, bo, nullptr, nullptr, flag, d_out, nullptr);
}

// Round 8
// 831.954 us; speedup vs baseline: 3.4914x; 1.0056x over previous
//
#include <hip/hip_runtime.h>
#include <math.h>

#define NH    12
#define SEQ   1024
#define DH    64
#define HID   768
#define BATCH 16
#define MTOT  (BATCH*SEQ)   // 16384
#define KDIM  HID           // 768
#define PSTRIDE 40          // attn LDS P row stride (80B, 16B-aligned)

typedef __attribute__((ext_vector_type(8))) short short8;
typedef __attribute__((ext_vector_type(4))) short short4v;
typedef __attribute__((ext_vector_type(8))) unsigned short ushort8;
typedef __attribute__((ext_vector_type(4))) float float4v;

__device__ __forceinline__ float bf2f(unsigned short u) {
    union { unsigned int i; float f; } v; v.i = ((unsigned int)u) << 16; return v.f;
}
__device__ __forceinline__ unsigned short f2bf(float f) {
    union { float f; unsigned int i; } v; v.f = f;
    unsigned int x = v.i;
    return (unsigned short)((x + 0x7FFFu + ((x >> 16) & 1u)) >> 16);  // RNE
}
__device__ __forceinline__ float loadf(const void* p, size_t i, bool f32) {
    return f32 ? ((const float*)p)[i] : bf2f(((const unsigned short*)p)[i]);
}

// async global->LDS, 16B/lane; LDS dest = wave-uniform base + lane*16.
__device__ __forceinline__ void gload_lds16(const void* g, void* l) {
    __builtin_amdgcn_global_load_lds(
        (const __attribute__((address_space(1))) unsigned int*)g,
        (__attribute__((address_space(3))) unsigned int*)l, 16, 0, 0);
}

// Runtime dtype classifier for x (flag=1 => fp32 inputs).
__global__ __launch_bounds__(256) void detect_kernel(
    const unsigned short* __restrict__ x, unsigned int* __restrict__ flag)
{
    __shared__ int cnt[256];
    const int tid = threadIdx.x;
    int local = 0;
    for (int i = tid; i < 1024; i += 256) {
        const unsigned short u = x[i];
        const int e = (u >> 7) & 0xFF;
        if ((e >= 96 && e <= 134) || ((u & 0x7FFF) == 0)) local++;
    }
    cnt[tid] = local;
    __syncthreads();
    for (int s = 128; s > 0; s >>= 1) {
        if (tid < s) cnt[tid] += cnt[tid + s];
        __syncthreads();
    }
    if (tid == 0) flag[0] = (cnt[0] < 900) ? 1u : 0u;
}

// Elementwise Ootomo split src -> hi (+ lo), N elems, 8/thread.
template<bool LO>
__global__ __launch_bounds__(256) void split_ker(
    const void* __restrict__ src, const unsigned int* __restrict__ flag,
    unsigned short* __restrict__ hi, unsigned short* __restrict__ lo, int n)
{
    const size_t i = ((size_t)blockIdx.x * 256 + threadIdx.x) * 8;
    if (i >= (size_t)n) return;
    ushort8 h, l;
    if (flag[0]) {
        const float* fp = (const float*)src + i;
        float4v f0 = *(const float4v*)fp, f1 = *(const float4v*)(fp + 4);
#pragma unroll
        for (int e = 0; e < 4; e++) {
            unsigned short h0 = f2bf(f0[e]), h1 = f2bf(f1[e]);
            h[e] = h0; h[4 + e] = h1;
            if (LO) { l[e] = f2bf(f0[e] - bf2f(h0)); l[4 + e] = f2bf(f1[e] - bf2f(h1)); }
        }
    } else {
        h = *(const ushort8*)((const unsigned short*)src + i);
        if (LO) {
#pragma unroll
            for (int e = 0; e < 8; e++) l[e] = 0;
        }
    }
    *(ushort8*)(hi + i) = h;
    if (LO) *(ushort8*)(lo + i) = l;
}

// W fragment load with in-register split (fallback path, W L2-resident).
template<bool WF32, bool PRECISE>
__device__ __forceinline__ void loadW(const void* __restrict__ W, size_t idx,
                                      short8& hi, short8& lo) {
    if constexpr (WF32) {
        const float* fp = (const float*)W + idx;
        float4v f0 = *(const float4v*)fp, f1 = *(const float4v*)(fp + 4);
#pragma unroll
        for (int e = 0; e < 4; e++) {
            unsigned short h0 = f2bf(f0[e]), h1 = f2bf(f1[e]);
            hi[e] = (short)h0; hi[4 + e] = (short)h1;
            if constexpr (PRECISE) {
                lo[e] = (short)f2bf(f0[e] - bf2f(h0));
                lo[4 + e] = (short)f2bf(f1[e] - bf2f(h1));
            }
        }
    } else {
        hi = *(const short8*)((const unsigned short*)W + idx);
        if constexpr (PRECISE) {
#pragma unroll
            for (int e = 0; e < 8; e++) lo[e] = 0;
        }
    }
}

// K-loop: A staged via global_load_lds; B either pre-split bf16 (WPRE) or
// runtime-converted (fallback).
template<bool PRECISE, bool WPRE, bool WF32>
__device__ __forceinline__ void staged_kloop(
    const unsigned short* __restrict__ Ahi, const unsigned short* __restrict__ Alo,
    const void* __restrict__ Wa, const void* __restrict__ Wb,
    unsigned short* sAhi, unsigned short* sAlo,
    int m_blk0, int n_base, int wid, int lane, float4v acc[4][4])
{
    const int tid  = wid * 64 + lane;
    const int quad = lane >> 4, l16 = lane & 15;
    const int m_off = (wid >> 1) * 64;
    const int srow = tid >> 2;
    const int scc  = tid & 3;

    for (int k0 = 0; k0 < KDIM; k0 += 32) {
#pragma unroll
        for (int it = 0; it < 2; it++) {
            const int r = it * 64 + srow;
            const size_t gidx = (size_t)(m_blk0 + r) * KDIM + k0 + scc * 8;
            const int loff = r * 32 + scc * 8;
            gload_lds16(Ahi + gidx, sAhi + loff);
            if constexpr (PRECISE) gload_lds16(Alo + gidx, sAlo + loff);
        }
        short8 bh[4], bl[4];
#pragma unroll
        for (int in = 0; in < 4; in++) {
            const size_t widx = (size_t)(n_base + in * 16 + l16) * KDIM + k0 + quad * 8;
            if constexpr (WPRE) {
                bh[in] = *(const short8*)((const unsigned short*)Wa + widx);
                if constexpr (PRECISE)
                    bl[in] = *(const short8*)((const unsigned short*)Wb + widx);
            } else {
                loadW<WF32, PRECISE>(Wa, widx, bh[in], bl[in]);
            }
        }
        __syncthreads();
        short8 ah[4], al[4];
#pragma unroll
        for (int im = 0; im < 4; im++) {
            const int r = m_off + im * 16 + l16;
            ah[im] = *(const short8*)(sAhi + r * 32 + quad * 8);
            if constexpr (PRECISE) al[im] = *(const short8*)(sAlo + r * 32 + quad * 8);
        }
#pragma unroll
        for (int im = 0; im < 4; im++)
#pragma unroll
            for (int in = 0; in < 4; in++) {
                acc[im][in] = __builtin_amdgcn_mfma_f32_16x16x32_bf16(
                    ah[im], bh[in], acc[im][in], 0, 0, 0);
                if constexpr (PRECISE) {
                    acc[im][in] = __builtin_amdgcn_mfma_f32_16x16x32_bf16(
                        al[im], bh[in], acc[im][in], 0, 0, 0);
                    acc[im][in] = __builtin_amdgcn_mfma_f32_16x16x32_bf16(
                        ah[im], bl[in], acc[im][in], 0, 0, 0);
                }
            }
        __syncthreads();
    }
}

// MODE 0: precise, +bias +rope *0.125 -> hi/lo bf16 (B,H,S,D)  (Q)
// MODE 1: precise, +bias +rope        -> hi/lo bf16 (B,H,S,D)  (K)
// MODE 2: fast,    +bias              -> bf16 V^T (B,H,D,S)
// MODE 3: fast,    +bias              -> d_out (M,N), dtype per flag
template<int MODE, bool WPRE>
__global__ __launch_bounds__(256) void gemm_staged(
    const unsigned short* __restrict__ Ahi, const unsigned short* __restrict__ Alo,
    const void* __restrict__ Wa, const void* __restrict__ Wb,
    const void* __restrict__ bias,
    const void* __restrict__ cosc, const void* __restrict__ sinc,
    const unsigned int* __restrict__ flag,
    void* __restrict__ Out, void* __restrict__ Out2)
{
    constexpr bool PRECISE = (MODE <= 1);
    __shared__ unsigned short sAhi[128 * 32];
    __shared__ unsigned short sAlo[PRECISE ? 128 * 32 : 64];

    const int tid  = threadIdx.x;
    const int wid  = tid >> 6;
    const int lane = tid & 63;
    const int quad = lane >> 4;
    const int l16  = lane & 15;
    const int m_blk0 = blockIdx.x * 128;
    const int m_blk = m_blk0 + (wid >> 1) * 64;
    const int n_base = blockIdx.y * 128 + (wid & 1) * 64;
    const bool f32 = (flag[0] != 0u);

    float4v acc[4][4];
#pragma unroll
    for (int i = 0; i < 4; i++)
#pragma unroll
        for (int j = 0; j < 4; j++) acc[i][j] = (float4v)(0.f);

    if constexpr (WPRE) {
        staged_kloop<PRECISE, true, false>(Ahi, Alo, Wa, Wb, sAhi, sAlo,
                                           m_blk0, n_base, wid, lane, acc);
    } else {
        if (f32) staged_kloop<PRECISE, false, true >(Ahi, Alo, Wa, Wb, sAhi, sAlo,
                                                     m_blk0, n_base, wid, lane, acc);
        else     staged_kloop<PRECISE, false, false>(Ahi, Alo, Wa, Wb, sAhi, sAlo,
                                                     m_blk0, n_base, wid, lane, acc);
    }

#pragma unroll
    for (int im = 0; im < 4; im++) {
#pragma unroll
        for (int in = 0; in < 4; in++) {
            const int col = n_base + in * 16 + l16;
            const float bval = loadf(bias, col, f32);
            if constexpr (MODE == 2) {
                short4v pk;
#pragma unroll
                for (int r = 0; r < 4; r++)
                    pk[r] = (short)f2bf(acc[im][in][r] + bval);
                const int row = m_blk + im * 16 + quad * 4;
                const int b = row >> 10, s = row & (SEQ - 1);
                const int h = col >> 6, d = col & (DH - 1);
                *(short4v*)((unsigned short*)Out +
                    ((size_t)(b * NH + h) * DH + d) * SEQ + s) = pk;
            } else if constexpr (MODE <= 1) {
                const int d  = col & (DH - 1);
                const int d2 = d >> 1;
#pragma unroll
                for (int r = 0; r < 4; r++) {
                    const int row = m_blk + im * 16 + quad * 4 + r;
                    const int s  = row & (SEQ - 1);
                    const float v = acc[im][in][r] + bval;
                    const float c  = loadf(cosc, s * (DH / 2) + d2, f32);
                    const float sn = loadf(sinc, s * (DH / 2) + d2, f32);
                    const float p = __shfl_xor(v, 1);  // lane^1 <-> d^1
                    float o = (d & 1) ? (v * c + p * sn) : (v * c - p * sn);
                    if (MODE == 0) o *= 0.125f;
                    // pair-pack: even lane stores (d, d+1) as one uint
                    const float po = __shfl_xor(o, 1);
                    if (!(l16 & 1)) {
                        const unsigned short h0 = f2bf(o), h1 = f2bf(po);
                        const unsigned short l0 = f2bf(o - bf2f(h0));
                        const unsigned short l1 = f2bf(po - bf2f(h1));
                        const int b = row >> 10, h = col >> 6;
                        const size_t idx = ((size_t)(b * NH + h) * SEQ + s) * DH + d;
                        *(unsigned int*)((unsigned short*)Out + idx) =
                            (unsigned int)h0 | ((unsigned int)h1 << 16);
                        *(unsigned int*)((unsigned short*)Out2 + idx) =
                            (unsigned int)l0 | ((unsigned int)l1 << 16);
                    }
                }
            } else {
#pragma unroll
                for (int r = 0; r < 4; r++) {
                    const int row = m_blk + im * 16 + quad * 4 + r;
                    const float v = acc[im][in][r] + bval;
                    if (f32) ((float*)Out)[(size_t)row * HID + col] = v;
                    else     ((unsigned short*)Out)[(size_t)row * HID + col] = f2bf(v);
                }
            }
        }
    }
}

// MFMA RSE attention: 1 wave = 32 queries (2x occupancy vs 64q), XCD-swizzled
// 1D grid so same-bh blocks share an XCD's L2 K/V copy.
__global__ __launch_bounds__(64, 4) void attn_mfma(
    const unsigned short* __restrict__ Qhi, const unsigned short* __restrict__ Qlo,
    const unsigned short* __restrict__ Khi, const unsigned short* __restrict__ Klo,
    const unsigned short* __restrict__ Vt,   // (B*H, D, S) bf16
    const void* __restrict__ lam_p, const unsigned int* __restrict__ flag,
    unsigned short* __restrict__ ctx)        // (B, S, HID) bf16
{
    const int lane = threadIdx.x;
    const int quad = lane >> 4;
    const int l16  = lane & 15;
    const int phys = blockIdx.x;                  // 6144 blocks
    const int virt = (phys & 7) * 768 + (phys >> 3);
    const int mb = virt & 31;                     // 32 query tiles of 32
    const int bh = virt >> 5;
    const bool f32 = (flag[0] != 0u);
    const float lam = loadf(lam_p, 0, f32);

    __shared__ unsigned short Plds[32 * PSTRIDE];

    short8 qh[2][2], ql[2][2];
#pragma unroll
    for (int qn = 0; qn < 2; qn++)
#pragma unroll
        for (int ks = 0; ks < 2; ks++) {
            const size_t base = ((size_t)bh * SEQ + (mb * 32 + qn * 16 + l16)) * DH
                                + ks * 32 + quad * 8;
            qh[qn][ks] = *(const short8*)(Qhi + base);
            ql[qn][ks] = *(const short8*)(Qlo + base);
        }

    float4v acc_o[4][2];
#pragma unroll
    for (int i = 0; i < 4; i++)
#pragma unroll
        for (int j = 0; j < 2; j++) acc_o[i][j] = (float4v)(0.f);

    float rem[2] = {1.f, 1.f};
    float l_i[2] = {0.f, 0.f};
    float m_i[2] = {-INFINITY, -INFINITY};
    float qf[2];
#pragma unroll
    for (int qn = 0; qn < 2; qn++) qf[qn] = (float)(mb * 32 + qn * 16 + l16);

    for (int kb = 0; kb < SEQ / 32; kb++) {
        short8 kh[2][2], kl[2][2];
#pragma unroll
        for (int kt = 0; kt < 2; kt++)
#pragma unroll
            for (int ks = 0; ks < 2; ks++) {
                const size_t base = ((size_t)bh * SEQ + (kb * 32 + kt * 16 + l16)) * DH
                                    + ks * 32 + quad * 8;
                kh[kt][ks] = *(const short8*)(Khi + base);
                kl[kt][ks] = *(const short8*)(Klo + base);
            }
        float4v s[2][2];
#pragma unroll
        for (int kt = 0; kt < 2; kt++)
#pragma unroll
            for (int qn = 0; qn < 2; qn++) s[kt][qn] = (float4v)(0.f);
#pragma unroll
        for (int ks = 0; ks < 2; ks++)
#pragma unroll
            for (int kt = 0; kt < 2; kt++)
#pragma unroll
                for (int qn = 0; qn < 2; qn++) {
                    s[kt][qn] = __builtin_amdgcn_mfma_f32_16x16x32_bf16(
                        kh[kt][ks], qh[qn][ks], s[kt][qn], 0, 0, 0);
                    s[kt][qn] = __builtin_amdgcn_mfma_f32_16x16x32_bf16(
                        kl[kt][ks], qh[qn][ks], s[kt][qn], 0, 0, 0);
                    s[kt][qn] = __builtin_amdgcn_mfma_f32_16x16x32_bf16(
                        kh[kt][ks], ql[qn][ks], s[kt][qn], 0, 0, 0);
                }

        float cons[2] = {0.f, 0.f};
        float mx[2] = {-INFINITY, -INFINITY};
#pragma unroll
        for (int kt = 0; kt < 2; kt++)
#pragma unroll
            for (int qn = 0; qn < 2; qn++)
#pragma unroll
                for (int r = 0; r < 4; r++) {
                    const float keyf = (float)(kb * 32 + kt * 16 + quad * 4 + r);
                    const float logit = s[kt][qn][r] - lam * fabsf(qf[qn] - keyf);
                    mx[qn] = fmaxf(mx[qn], logit);
                    // no clamp: exp2 saturates to the same sigmoid limits
                    const float beta = __builtin_amdgcn_rcpf(
                        1.f + exp2f(-logit * 1.44269504088896f));
                    const float w = beta * rem[qn];
                    cons[qn] += w;
                    s[kt][qn][r] = w;
                }
#pragma unroll
        for (int qn = 0; qn < 2; qn++) {
            cons[qn] += __shfl_xor(cons[qn], 16);
            cons[qn] += __shfl_xor(cons[qn], 32);
            mx[qn] = fmaxf(mx[qn], __shfl_xor(mx[qn], 16));
            mx[qn] = fmaxf(mx[qn], __shfl_xor(mx[qn], 32));
        }

#pragma unroll
        for (int kt = 0; kt < 2; kt++)
#pragma unroll
            for (int qn = 0; qn < 2; qn++) {
                short4v pk;
#pragma unroll
                for (int r = 0; r < 4; r++) pk[r] = (short)f2bf(s[kt][qn][r]);
                *(short4v*)(Plds + (qn * 16 + l16) * PSTRIDE + kt * 16 + quad * 4) = pk;
            }
        __syncthreads();

        short8 vf[4], pf[2];
#pragma unroll
        for (int dt = 0; dt < 4; dt++)
            vf[dt] = *(const short8*)(Vt + ((size_t)bh * DH + dt * 16 + l16) * SEQ
                                      + kb * 32 + quad * 8);
#pragma unroll
        for (int jn = 0; jn < 2; jn++)
            pf[jn] = *(const short8*)(Plds + (jn * 16 + l16) * PSTRIDE + quad * 8);
#pragma unroll
        for (int dt = 0; dt < 4; dt++)
#pragma unroll
            for (int jn = 0; jn < 2; jn++)
                acc_o[dt][jn] = __builtin_amdgcn_mfma_f32_16x16x32_bf16(
                    vf[dt], pf[jn], acc_o[dt][jn], 0, 0, 0);
        __syncthreads();

#pragma unroll
        for (int qn = 0; qn < 2; qn++) {
            rem[qn] = fmaxf(rem[qn] * (1.f - cons[qn]), 1e-6f);
            const float m_new = fmaxf(m_i[qn], mx[qn]);
            const float alpha = exp2f(m_i[qn] - m_new);
            l_i[qn] = l_i[qn] * alpha + cons[qn];
            m_i[qn] = m_new;
        }
    }

    const int b = bh / NH, h = bh % NH;
    float inv[2];
#pragma unroll
    for (int jn = 0; jn < 2; jn++)
        inv[jn] = __builtin_amdgcn_rcpf(fmaxf(l_i[jn], 1e-6f));
#pragma unroll
    for (int dt = 0; dt < 4; dt++)
#pragma unroll
        for (int jn = 0; jn < 2; jn++) {
            short4v pk;
#pragma unroll
            for (int r = 0; r < 4; r++)
                pk[r] = (short)f2bf(acc_o[dt][jn][r] * inv[jn]);
            const int q_g = mb * 32 + jn * 16 + l16;
            *(short4v*)(ctx + ((size_t)(b * SEQ + q_g) * HID
                               + h * DH + dt * 16 + quad * 4)) = pk;
        }
}

extern "C" void kernel_launch(void* const* d_in, const int* in_sizes, int n_in,
                              void* d_out, int out_size, void* d_ws, size_t ws_size,
                              hipStream_t stream) {
    const void* x    = d_in[0];
    const void* Wq   = d_in[1];
    const void* bq   = d_in[2];
    const void* Wk   = d_in[3];
    const void* bk   = d_in[4];
    const void* Wv   = d_in[5];
    const void* bv   = d_in[6];
    const void* Wo   = d_in[7];
    const void* bo   = d_in[8];
    const void* lam  = d_in[9];
    const void* cosc = d_in[10];
    const void* sinc = d_in[11];

    const size_t NELEM = (size_t)MTOT * HID;   // 12.58M
    const size_t WELEM = (size_t)HID * HID;    // 589824
    unsigned int* flag = (unsigned int*)d_ws;
    unsigned short* Xhi = (unsigned short*)((char*)d_ws + 64);
    unsigned short* Xlo = Xhi + NELEM;   // reused as Vt after K GEMM
    unsigned short* Qhi = Xlo + NELEM;
    unsigned short* Qlo = Qhi + NELEM;
    unsigned short* Wqh = Qlo + NELEM;   // W splits: +7.08MB past 100.7MB
    unsigned short* Wql = Wqh + WELEM;
    unsigned short* Wkh = Wql + WELEM;
    unsigned short* Wkl = Wkh + WELEM;
    unsigned short* Wvh = Wkl + WELEM;
    unsigned short* Woh = Wvh + WELEM;
    const size_t NEED = 64 + 4 * NELEM * 2 + 6 * WELEM * 2;
    const bool wpre = (ws_size >= NEED);

    unsigned short* Vt  = Xlo;           // xlo dead after K GEMM
    unsigned short* Ctx = Xhi;           // xhi dead after V GEMM
    unsigned short* Khi = (unsigned short*)d_out;  // dead before final GEMM
    unsigned short* Klo = Khi + NELEM;

    detect_kernel<<<1, 256, 0, stream>>>((const unsigned short*)x, flag);
    split_ker<true><<<(MTOT * KDIM) / 2048, 256, 0, stream>>>(x, flag, Xhi, Xlo, MTOT * KDIM);

    dim3 gg(MTOT / 128, HID / 128), gb(256);
    if (wpre) {
        const int wb = (int)(WELEM / 2048);
        split_ker<true ><<<wb, 256, 0, stream>>>(Wq, flag, Wqh, Wql, (int)WELEM);
        split_ker<true ><<<wb, 256, 0, stream>>>(Wk, flag, Wkh, Wkl, (int)WELEM);
        split_ker<false><<<wb, 256, 0, stream>>>(Wv, flag, Wvh, nullptr, (int)WELEM);
        split_ker<false><<<wb, 256, 0, stream>>>(Wo, flag, Woh, nullptr, (int)WELEM);
        gemm_staged<0, true><<<gg, gb, 0, stream>>>(Xhi, Xlo, Wqh, Wql, bq, cosc, sinc, flag, Qhi, Qlo);
        gemm_staged<1, true><<<gg, gb, 0, stream>>>(Xhi, Xlo, Wkh, Wkl, bk, cosc, sinc, flag, Khi, Klo);
        gemm_staged<2, true><<<gg, gb, 0, stream>>>(Xhi, nullptr, Wvh, nullptr, bv, nullptr, nullptr, flag, Vt, nullptr);
    } else {
        gemm_staged<0, false><<<gg, gb, 0, stream>>>(Xhi, Xlo, Wq, nullptr, bq, cosc, sinc, flag, Qhi, Qlo);
        gemm_staged<1, false><<<gg, gb, 0, stream>>>(Xhi, Xlo, Wk, nullptr, bk, cosc, sinc, flag, Khi, Klo);
        gemm_staged<2, false><<<gg, gb, 0, stream>>>(Xhi, nullptr, Wv, nullptr, bv, nullptr, nullptr, flag, Vt, nullptr);
    }
    attn_mfma<<<dim3(32 * BATCH * NH), 64, 0, stream>>>(
        Qhi, Qlo, Khi, Klo, Vt, lam, flag, Ctx);
    if (wpre)
        gemm_staged<3, true><<<gg, gb, 0, stream>>>(Ctx, nullptr, Woh, nullptr, bo, nullptr, nullptr, flag, d_out, nullptr);
    else
        gemm_staged<3, false><<<gg, gb, 0, stream>>>(Ctx, nullptr, Wo, nullptr, bo, nullptr, nullptr, flag, d_out, nullptr);
}

// Round 9
// 727.183 us; speedup vs baseline: 3.9945x; 1.1441x over previous
//
#include <hip/hip_runtime.h>
#include <math.h>

#define NH    12
#define SEQ   1024
#define DH    64
#define HID   768
#define BATCH 16
#define MTOT  (BATCH*SEQ)   // 16384
#define KDIM  HID           // 768
#define PSTRIDE 40          // attn LDS P row stride (80B, 16B-aligned)

typedef __attribute__((ext_vector_type(8))) short short8;
typedef __attribute__((ext_vector_type(4))) short short4v;
typedef __attribute__((ext_vector_type(8))) unsigned short ushort8;
typedef __attribute__((ext_vector_type(4))) float float4v;

__device__ __forceinline__ float bf2f(unsigned short u) {
    union { unsigned int i; float f; } v; v.i = ((unsigned int)u) << 16; return v.f;
}
__device__ __forceinline__ unsigned short f2bf(float f) {
    union { float f; unsigned int i; } v; v.f = f;
    unsigned int x = v.i;
    return (unsigned short)((x + 0x7FFFu + ((x >> 16) & 1u)) >> 16);  // RNE
}
__device__ __forceinline__ float loadf(const void* p, size_t i, bool f32) {
    return f32 ? ((const float*)p)[i] : bf2f(((const unsigned short*)p)[i]);
}

// async global->LDS, 16B/lane; LDS dest = wave-uniform base + lane*16.
__device__ __forceinline__ void gload_lds16(const void* g, void* l) {
    __builtin_amdgcn_global_load_lds(
        (const __attribute__((address_space(1))) unsigned int*)g,
        (__attribute__((address_space(3))) unsigned int*)l, 16, 0, 0);
}

// Runtime dtype classifier for x (flag=1 => fp32 inputs).
__global__ __launch_bounds__(256) void detect_kernel(
    const unsigned short* __restrict__ x, unsigned int* __restrict__ flag)
{
    __shared__ int cnt[256];
    const int tid = threadIdx.x;
    int local = 0;
    for (int i = tid; i < 1024; i += 256) {
        const unsigned short u = x[i];
        const int e = (u >> 7) & 0xFF;
        if ((e >= 96 && e <= 134) || ((u & 0x7FFF) == 0)) local++;
    }
    cnt[tid] = local;
    __syncthreads();
    for (int s = 128; s > 0; s >>= 1) {
        if (tid < s) cnt[tid] += cnt[tid + s];
        __syncthreads();
    }
    if (tid == 0) flag[0] = (cnt[0] < 900) ? 1u : 0u;
}

// Elementwise Ootomo split src -> hi (+ lo), N elems, 8/thread.
template<bool LO>
__global__ __launch_bounds__(256) void split_ker(
    const void* __restrict__ src, const unsigned int* __restrict__ flag,
    unsigned short* __restrict__ hi, unsigned short* __restrict__ lo, int n)
{
    const size_t i = ((size_t)blockIdx.x * 256 + threadIdx.x) * 8;
    if (i >= (size_t)n) return;
    ushort8 h, l;
    if (flag[0]) {
        const float* fp = (const float*)src + i;
        float4v f0 = *(const float4v*)fp, f1 = *(const float4v*)(fp + 4);
#pragma unroll
        for (int e = 0; e < 4; e++) {
            unsigned short h0 = f2bf(f0[e]), h1 = f2bf(f1[e]);
            h[e] = h0; h[4 + e] = h1;
            if (LO) { l[e] = f2bf(f0[e] - bf2f(h0)); l[4 + e] = f2bf(f1[e] - bf2f(h1)); }
        }
    } else {
        h = *(const ushort8*)((const unsigned short*)src + i);
        if (LO) {
#pragma unroll
            for (int e = 0; e < 8; e++) l[e] = 0;
        }
    }
    *(ushort8*)(hi + i) = h;
    if (LO) *(ushort8*)(lo + i) = l;
}

// W fragment load with in-register split (fallback path, W L2-resident).
template<bool WF32, bool PRECISE>
__device__ __forceinline__ void loadW(const void* __restrict__ W, size_t idx,
                                      short8& hi, short8& lo) {
    if constexpr (WF32) {
        const float* fp = (const float*)W + idx;
        float4v f0 = *(const float4v*)fp, f1 = *(const float4v*)(fp + 4);
#pragma unroll
        for (int e = 0; e < 4; e++) {
            unsigned short h0 = f2bf(f0[e]), h1 = f2bf(f1[e]);
            hi[e] = (short)h0; hi[4 + e] = (short)h1;
            if constexpr (PRECISE) {
                lo[e] = (short)f2bf(f0[e] - bf2f(h0));
                lo[4 + e] = (short)f2bf(f1[e] - bf2f(h1));
            }
        }
    } else {
        hi = *(const short8*)((const unsigned short*)W + idx);
        if constexpr (PRECISE) {
#pragma unroll
            for (int e = 0; e < 8; e++) lo[e] = 0;
        }
    }
}

// K-loop: A staged via global_load_lds; B either pre-split bf16 (WPRE) or
// runtime-converted (fallback).
template<bool PRECISE, bool WPRE, bool WF32>
__device__ __forceinline__ void staged_kloop(
    const unsigned short* __restrict__ Ahi, const unsigned short* __restrict__ Alo,
    const void* __restrict__ Wa, const void* __restrict__ Wb,
    unsigned short* sAhi, unsigned short* sAlo,
    int m_blk0, int n_base, int wid, int lane, float4v acc[4][4])
{
    const int tid  = wid * 64 + lane;
    const int quad = lane >> 4, l16 = lane & 15;
    const int m_off = (wid >> 1) * 64;
    const int srow = tid >> 2;
    const int scc  = tid & 3;

    for (int k0 = 0; k0 < KDIM; k0 += 32) {
#pragma unroll
        for (int it = 0; it < 2; it++) {
            const int r = it * 64 + srow;
            const size_t gidx = (size_t)(m_blk0 + r) * KDIM + k0 + scc * 8;
            const int loff = r * 32 + scc * 8;
            gload_lds16(Ahi + gidx, sAhi + loff);
            if constexpr (PRECISE) gload_lds16(Alo + gidx, sAlo + loff);
        }
        short8 bh[4], bl[4];
#pragma unroll
        for (int in = 0; in < 4; in++) {
            const size_t widx = (size_t)(n_base + in * 16 + l16) * KDIM + k0 + quad * 8;
            if constexpr (WPRE) {
                bh[in] = *(const short8*)((const unsigned short*)Wa + widx);
                if constexpr (PRECISE)
                    bl[in] = *(const short8*)((const unsigned short*)Wb + widx);
            } else {
                loadW<WF32, PRECISE>(Wa, widx, bh[in], bl[in]);
            }
        }
        __syncthreads();
        short8 ah[4], al[4];
#pragma unroll
        for (int im = 0; im < 4; im++) {
            const int r = m_off + im * 16 + l16;
            ah[im] = *(const short8*)(sAhi + r * 32 + quad * 8);
            if constexpr (PRECISE) al[im] = *(const short8*)(sAlo + r * 32 + quad * 8);
        }
#pragma unroll
        for (int im = 0; im < 4; im++)
#pragma unroll
            for (int in = 0; in < 4; in++) {
                acc[im][in] = __builtin_amdgcn_mfma_f32_16x16x32_bf16(
                    ah[im], bh[in], acc[im][in], 0, 0, 0);
                if constexpr (PRECISE) {
                    acc[im][in] = __builtin_amdgcn_mfma_f32_16x16x32_bf16(
                        al[im], bh[in], acc[im][in], 0, 0, 0);
                    acc[im][in] = __builtin_amdgcn_mfma_f32_16x16x32_bf16(
                        ah[im], bl[in], acc[im][in], 0, 0, 0);
                }
            }
        __syncthreads();
    }
}

// MODE 0: precise, +bias +rope *0.125 -> hi/lo bf16 (B,H,S,D)  (Q)
// MODE 1: precise, +bias +rope        -> hi/lo bf16 (B,H,S,D)  (K)
// MODE 2: fast,    +bias              -> bf16 V^T (B,H,D,S)
// MODE 3: fast,    +bias              -> d_out (M,N), dtype per flag
template<int MODE, bool WPRE>
__global__ __launch_bounds__(256) void gemm_staged(
    const unsigned short* __restrict__ Ahi, const unsigned short* __restrict__ Alo,
    const void* __restrict__ Wa, const void* __restrict__ Wb,
    const void* __restrict__ bias,
    const void* __restrict__ cosc, const void* __restrict__ sinc,
    const unsigned int* __restrict__ flag,
    void* __restrict__ Out, void* __restrict__ Out2)
{
    constexpr bool PRECISE = (MODE <= 1);
    __shared__ unsigned short sAhi[128 * 32];
    __shared__ unsigned short sAlo[PRECISE ? 128 * 32 : 64];

    const int tid  = threadIdx.x;
    const int wid  = tid >> 6;
    const int lane = tid & 63;
    const int quad = lane >> 4;
    const int l16  = lane & 15;
    const int m_blk0 = blockIdx.x * 128;
    const int m_blk = m_blk0 + (wid >> 1) * 64;
    const int n_base = blockIdx.y * 128 + (wid & 1) * 64;
    const bool f32 = (flag[0] != 0u);

    float4v acc[4][4];
#pragma unroll
    for (int i = 0; i < 4; i++)
#pragma unroll
        for (int j = 0; j < 4; j++) acc[i][j] = (float4v)(0.f);

    if constexpr (WPRE) {
        staged_kloop<PRECISE, true, false>(Ahi, Alo, Wa, Wb, sAhi, sAlo,
                                           m_blk0, n_base, wid, lane, acc);
    } else {
        if (f32) staged_kloop<PRECISE, false, true >(Ahi, Alo, Wa, Wb, sAhi, sAlo,
                                                     m_blk0, n_base, wid, lane, acc);
        else     staged_kloop<PRECISE, false, false>(Ahi, Alo, Wa, Wb, sAhi, sAlo,
                                                     m_blk0, n_base, wid, lane, acc);
    }

#pragma unroll
    for (int im = 0; im < 4; im++) {
#pragma unroll
        for (int in = 0; in < 4; in++) {
            const int col = n_base + in * 16 + l16;
            const float bval = loadf(bias, col, f32);
            if constexpr (MODE == 2) {
                short4v pk;
#pragma unroll
                for (int r = 0; r < 4; r++)
                    pk[r] = (short)f2bf(acc[im][in][r] + bval);
                const int row = m_blk + im * 16 + quad * 4;
                const int b = row >> 10, s = row & (SEQ - 1);
                const int h = col >> 6, d = col & (DH - 1);
                *(short4v*)((unsigned short*)Out +
                    ((size_t)(b * NH + h) * DH + d) * SEQ + s) = pk;
            } else if constexpr (MODE <= 1) {
                const int d  = col & (DH - 1);
                const int d2 = d >> 1;
#pragma unroll
                for (int r = 0; r < 4; r++) {
                    const int row = m_blk + im * 16 + quad * 4 + r;
                    const int s  = row & (SEQ - 1);
                    const float v = acc[im][in][r] + bval;
                    const float c  = loadf(cosc, s * (DH / 2) + d2, f32);
                    const float sn = loadf(sinc, s * (DH / 2) + d2, f32);
                    const float p = __shfl_xor(v, 1);  // lane^1 <-> d^1
                    float o = (d & 1) ? (v * c + p * sn) : (v * c - p * sn);
                    if (MODE == 0) o *= 0.125f;
                    const float po = __shfl_xor(o, 1);
                    if (!(l16 & 1)) {
                        const unsigned short h0 = f2bf(o), h1 = f2bf(po);
                        const unsigned short l0 = f2bf(o - bf2f(h0));
                        const unsigned short l1 = f2bf(po - bf2f(h1));
                        const int b = row >> 10, h = col >> 6;
                        const size_t idx = ((size_t)(b * NH + h) * SEQ + s) * DH + d;
                        *(unsigned int*)((unsigned short*)Out + idx) =
                            (unsigned int)h0 | ((unsigned int)h1 << 16);
                        *(unsigned int*)((unsigned short*)Out2 + idx) =
                            (unsigned int)l0 | ((unsigned int)l1 << 16);
                    }
                }
            } else {
#pragma unroll
                for (int r = 0; r < 4; r++) {
                    const int row = m_blk + im * 16 + quad * 4 + r;
                    const float v = acc[im][in][r] + bval;
                    if (f32) ((float*)Out)[(size_t)row * HID + col] = v;
                    else     ((unsigned short*)Out)[(size_t)row * HID + col] = f2bf(v);
                }
            }
        }
    }
}

// MFMA RSE attention v3: 4 waves/block, 64q each (256 q/block, 768 blocks).
// K/V per 32-key chunk staged ONCE per block via global_load_lds into a
// double-buffered, XOR-swizzled LDS slab; fragments via ds_read_b128.
// One barrier per chunk; P is per-wave-private LDS.
__global__ __launch_bounds__(256, 2) void attn_mfma(
    const unsigned short* __restrict__ Qhi, const unsigned short* __restrict__ Qlo,
    const unsigned short* __restrict__ Khi, const unsigned short* __restrict__ Klo,
    const unsigned short* __restrict__ Vt,   // (B*H, D, S) bf16
    const void* __restrict__ lam_p, const unsigned int* __restrict__ flag,
    unsigned short* __restrict__ ctx)        // (B, S, HID) bf16
{
    const int tid  = threadIdx.x;
    const int wid  = tid >> 6;
    const int lane = tid & 63;
    const int quad = lane >> 4;
    const int l16  = lane & 15;
    const int phys = blockIdx.x;                   // 768 blocks
    const int virt = (phys & 7) * 96 + (phys >> 3);  // XCD-contiguous bh runs
    const int bh   = virt >> 2;                    // 4 q-blocks per bh
    const int q0   = (virt & 3) * 256 + wid * 64;  // wave's query base
    const bool f32 = (flag[0] != 0u);
    const float lam = loadf(lam_p, 0, f32);

    // [buf][ Khi 2048 | Klo 2048 | V 2048 ] ushorts (12KB per buffer)
    __shared__ unsigned short KV[2][6144];
    __shared__ unsigned short Pl[4][64 * PSTRIDE];  // per-wave P slab

    // staging thread mapping (whole block stages 12KB in 3 issues/thread)
    const int krow = tid >> 3, kch = tid & 7;
    const int kgch = kch ^ (krow & 7);             // XOR swizzle (read-side spread)
    const int vrow = tid >> 2, vch = tid & 3;
    const int vgch = vch ^ (vrow & 3);

    #define STAGE(kb_, buf_) do {                                            \
        const size_t gk = ((size_t)bh * SEQ + (kb_) * 32 + krow) * DH + kgch * 8; \
        gload_lds16(Khi + gk, &KV[buf_][0]    + tid * 8);                    \
        gload_lds16(Klo + gk, &KV[buf_][2048] + tid * 8);                    \
        const size_t gv = ((size_t)bh * DH + vrow) * SEQ + (kb_) * 32 + vgch * 8; \
        gload_lds16(Vt + gv, &KV[buf_][4096] + tid * 8);                     \
    } while (0)

    // resident Q fragments (B-operand), hi+lo
    short8 qh[4][2], ql[4][2];
#pragma unroll
    for (int qn = 0; qn < 4; qn++)
#pragma unroll
        for (int ks = 0; ks < 2; ks++) {
            const size_t base = ((size_t)bh * SEQ + (q0 + qn * 16 + l16)) * DH
                                + ks * 32 + quad * 8;
            qh[qn][ks] = *(const short8*)(Qhi + base);
            ql[qn][ks] = *(const short8*)(Qlo + base);
        }

    float4v acc_o[4][4];
#pragma unroll
    for (int i = 0; i < 4; i++)
#pragma unroll
        for (int j = 0; j < 4; j++) acc_o[i][j] = (float4v)(0.f);

    float rem[4] = {1.f, 1.f, 1.f, 1.f};
    float l_i[4] = {0.f, 0.f, 0.f, 0.f};
    float m_i[4] = {-INFINITY, -INFINITY, -INFINITY, -INFINITY};
    float qf[4];
#pragma unroll
    for (int qn = 0; qn < 4; qn++) qf[qn] = (float)(q0 + qn * 16 + l16);

    STAGE(0, 0);
    __syncthreads();

    for (int kb = 0; kb < SEQ / 32; kb++) {
        const int buf = kb & 1;
        if (kb + 1 < SEQ / 32) STAGE(kb + 1, buf ^ 1);

        // ---- K fragments from LDS (swizzled) ----
        short8 kh[2][2], kl[2][2];
#pragma unroll
        for (int kt = 0; kt < 2; kt++)
#pragma unroll
            for (int ks = 0; ks < 2; ks++) {
                const int off = (kt * 16 + l16) * 64
                                + ((ks * 4 + quad) ^ (l16 & 7)) * 8;
                kh[kt][ks] = *(const short8*)(&KV[buf][0]    + off);
                kl[kt][ks] = *(const short8*)(&KV[buf][2048] + off);
            }

        // ---- S^T = K·Q^T (bf16x3) ----
        float4v s[2][4];
#pragma unroll
        for (int kt = 0; kt < 2; kt++)
#pragma unroll
            for (int qn = 0; qn < 4; qn++) s[kt][qn] = (float4v)(0.f);
#pragma unroll
        for (int ks = 0; ks < 2; ks++)
#pragma unroll
            for (int kt = 0; kt < 2; kt++)
#pragma unroll
                for (int qn = 0; qn < 4; qn++) {
                    s[kt][qn] = __builtin_amdgcn_mfma_f32_16x16x32_bf16(
                        kh[kt][ks], qh[qn][ks], s[kt][qn], 0, 0, 0);
                    s[kt][qn] = __builtin_amdgcn_mfma_f32_16x16x32_bf16(
                        kl[kt][ks], qh[qn][ks], s[kt][qn], 0, 0, 0);
                    s[kt][qn] = __builtin_amdgcn_mfma_f32_16x16x32_bf16(
                        kh[kt][ks], ql[qn][ks], s[kt][qn], 0, 0, 0);
                }

        // ---- sigmoid / decay / stats ----
        float cons[4] = {0.f, 0.f, 0.f, 0.f};
        float mx[4] = {-INFINITY, -INFINITY, -INFINITY, -INFINITY};
#pragma unroll
        for (int kt = 0; kt < 2; kt++)
#pragma unroll
            for (int qn = 0; qn < 4; qn++)
#pragma unroll
                for (int r = 0; r < 4; r++) {
                    const float keyf = (float)(kb * 32 + kt * 16 + quad * 4 + r);
                    const float logit = s[kt][qn][r] - lam * fabsf(qf[qn] - keyf);
                    mx[qn] = fmaxf(mx[qn], logit);
                    const float beta = __builtin_amdgcn_rcpf(
                        1.f + exp2f(-logit * 1.44269504088896f));
                    const float w = beta * rem[qn];
                    cons[qn] += w;
                    s[kt][qn][r] = w;
                }
#pragma unroll
        for (int qn = 0; qn < 4; qn++) {
            cons[qn] += __shfl_xor(cons[qn], 16);
            cons[qn] += __shfl_xor(cons[qn], 32);
            mx[qn] = fmaxf(mx[qn], __shfl_xor(mx[qn], 16));
            mx[qn] = fmaxf(mx[qn], __shfl_xor(mx[qn], 32));
        }

        // ---- P^T to per-wave LDS slab (no cross-wave sync needed) ----
#pragma unroll
        for (int kt = 0; kt < 2; kt++)
#pragma unroll
            for (int qn = 0; qn < 4; qn++) {
                short4v pk;
#pragma unroll
                for (int r = 0; r < 4; r++) pk[r] = (short)f2bf(s[kt][qn][r]);
                *(short4v*)(Pl[wid] + (qn * 16 + l16) * PSTRIDE
                            + kt * 16 + quad * 4) = pk;
            }

        // ---- O^T += V^T·P^T ----
        short8 vf[4], pf[4];
#pragma unroll
        for (int dt = 0; dt < 4; dt++) {
            const int off = (dt * 16 + l16) * 32 + (quad ^ (l16 & 3)) * 8;
            vf[dt] = *(const short8*)(&KV[buf][4096] + off);
        }
#pragma unroll
        for (int jn = 0; jn < 4; jn++)
            pf[jn] = *(const short8*)(Pl[wid] + (jn * 16 + l16) * PSTRIDE + quad * 8);
#pragma unroll
        for (int dt = 0; dt < 4; dt++)
#pragma unroll
            for (int jn = 0; jn < 4; jn++)
                acc_o[dt][jn] = __builtin_amdgcn_mfma_f32_16x16x32_bf16(
                    vf[dt], pf[jn], acc_o[dt][jn], 0, 0, 0);

        // ---- state update ----
#pragma unroll
        for (int qn = 0; qn < 4; qn++) {
            rem[qn] = fmaxf(rem[qn] * (1.f - cons[qn]), 1e-6f);
            const float m_new = fmaxf(m_i[qn], mx[qn]);
            const float alpha = exp2f(m_i[qn] - m_new);
            l_i[qn] = l_i[qn] * alpha + cons[qn];
            m_i[qn] = m_new;
        }

        __syncthreads();   // drains stage(kb+1) loads; protects buf reuse
    }

    const int b = bh / NH, h = bh % NH;
    float inv[4];
#pragma unroll
    for (int jn = 0; jn < 4; jn++)
        inv[jn] = __builtin_amdgcn_rcpf(fmaxf(l_i[jn], 1e-6f));
#pragma unroll
    for (int dt = 0; dt < 4; dt++)
#pragma unroll
        for (int jn = 0; jn < 4; jn++) {
            short4v pk;
#pragma unroll
            for (int r = 0; r < 4; r++)
                pk[r] = (short)f2bf(acc_o[dt][jn][r] * inv[jn]);
            const int q_g = q0 + jn * 16 + l16;
            *(short4v*)(ctx + ((size_t)(b * SEQ + q_g) * HID
                               + h * DH + dt * 16 + quad * 4)) = pk;
        }
    #undef STAGE
}

extern "C" void kernel_launch(void* const* d_in, const int* in_sizes, int n_in,
                              void* d_out, int out_size, void* d_ws, size_t ws_size,
                              hipStream_t stream) {
    const void* x    = d_in[0];
    const void* Wq   = d_in[1];
    const void* bq   = d_in[2];
    const void* Wk   = d_in[3];
    const void* bk   = d_in[4];
    const void* Wv   = d_in[5];
    const void* bv   = d_in[6];
    const void* Wo   = d_in[7];
    const void* bo   = d_in[8];
    const void* lam  = d_in[9];
    const void* cosc = d_in[10];
    const void* sinc = d_in[11];

    const size_t NELEM = (size_t)MTOT * HID;   // 12.58M
    const size_t WELEM = (size_t)HID * HID;    // 589824
    unsigned int* flag = (unsigned int*)d_ws;
    unsigned short* Xhi = (unsigned short*)((char*)d_ws + 64);
    unsigned short* Xlo = Xhi + NELEM;   // reused as Vt after K GEMM
    unsigned short* Qhi = Xlo + NELEM;
    unsigned short* Qlo = Qhi + NELEM;
    unsigned short* Wqh = Qlo + NELEM;   // W splits: +7.08MB past 100.7MB
    unsigned short* Wql = Wqh + WELEM;
    unsigned short* Wkh = Wql + WELEM;
    unsigned short* Wkl = Wkh + WELEM;
    unsigned short* Wvh = Wkl + WELEM;
    unsigned short* Woh = Wvh + WELEM;
    const size_t NEED = 64 + 4 * NELEM * 2 + 6 * WELEM * 2;
    const bool wpre = (ws_size >= NEED);

    unsigned short* Vt  = Xlo;           // xlo dead after K GEMM
    unsigned short* Ctx = Xhi;           // xhi dead after V GEMM
    unsigned short* Khi = (unsigned short*)d_out;  // dead before final GEMM
    unsigned short* Klo = Khi + NELEM;

    detect_kernel<<<1, 256, 0, stream>>>((const unsigned short*)x, flag);
    split_ker<true><<<(MTOT * KDIM) / 2048, 256, 0, stream>>>(x, flag, Xhi, Xlo, MTOT * KDIM);

    dim3 gg(MTOT / 128, HID / 128), gb(256);
    if (wpre) {
        const int wb = (int)(WELEM / 2048);
        split_ker<true ><<<wb, 256, 0, stream>>>(Wq, flag, Wqh, Wql, (int)WELEM);
        split_ker<true ><<<wb, 256, 0, stream>>>(Wk, flag, Wkh, Wkl, (int)WELEM);
        split_ker<false><<<wb, 256, 0, stream>>>(Wv, flag, Wvh, nullptr, (int)WELEM);
        split_ker<false><<<wb, 256, 0, stream>>>(Wo, flag, Woh, nullptr, (int)WELEM);
        gemm_staged<0, true><<<gg, gb, 0, stream>>>(Xhi, Xlo, Wqh, Wql, bq, cosc, sinc, flag, Qhi, Qlo);
        gemm_staged<1, true><<<gg, gb, 0, stream>>>(Xhi, Xlo, Wkh, Wkl, bk, cosc, sinc, flag, Khi, Klo);
        gemm_staged<2, true><<<gg, gb, 0, stream>>>(Xhi, nullptr, Wvh, nullptr, bv, nullptr, nullptr, flag, Vt, nullptr);
    } else {
        gemm_staged<0, false><<<gg, gb, 0, stream>>>(Xhi, Xlo, Wq, nullptr, bq, cosc, sinc, flag, Qhi, Qlo);
        gemm_staged<1, false><<<gg, gb, 0, stream>>>(Xhi, Xlo, Wk, nullptr, bk, cosc, sinc, flag, Khi, Klo);
        gemm_staged<2, false><<<gg, gb, 0, stream>>>(Xhi, nullptr, Wv, nullptr, bv, nullptr, nullptr, flag, Vt, nullptr);
    }
    attn_mfma<<<dim3(4 * BATCH * NH), 256, 0, stream>>>(
        Qhi, Qlo, Khi, Klo, Vt, lam, flag, Ctx);
    if (wpre)
        gemm_staged<3, true><<<gg, gb, 0, stream>>>(Ctx, nullptr, Woh, nullptr, bo, nullptr, nullptr, flag, d_out, nullptr);
    else
        gemm_staged<3, false><<<gg, gb, 0, stream>>>(Ctx, nullptr, Wo, nullptr, bo, nullptr, nullptr, flag, d_out, nullptr);
}